// Round 1
// baseline (88248.785 us; speedup 1.0000x reference)
//
#include <hip/hip_runtime.h>
#include <hip/hip_cooperative_groups.h>
#include <math.h>

namespace cg = cooperative_groups;

// NSE recurrent model, B=32, L=1024, K=256 — persistent cooperative kernel.
// mem (33.5MB) lives entirely in aggregate LDS: 256 blocks x 128 rows x 1KB = 32MB.
// Block g: phase A owns mem rows of (b = g>>3, l = (g&7)*128 .. +128), scores kept in regs.
// Phase B: block (bg = g>>6, cg = g&63) computes writer+reader gates for 8 b's x 4 j's,
// batched over b so transposed weights (WfT[col][k], rWT[col][k]) are reused 8x from L1.
// 2 grid.sync() per step; zero HBM traffic for mem.

#define Bb 32
#define LL 1024
#define KK 256

__device__ __forceinline__ float sigf(float v) { return 1.0f / (1.0f + __expf(-v)); }

// ---------------- one-time: WfT = [cW@wWx ; wWh]^T (per col 768), bf = cb@wWx + wb,
// ---------------- rWT = [rWx ; rWh]^T (per col 512)
__global__ __launch_bounds__(256) void k_pre(
    const float* __restrict__ cW, const float* __restrict__ cb,
    const float* __restrict__ wWx, const float* __restrict__ wb,
    const float* __restrict__ rWx, const float* __restrict__ rWh,
    const float* __restrict__ wWh,
    float* __restrict__ WfT, float* __restrict__ rWT, float* __restrict__ bfv) {
    int bid = blockIdx.x, tid = threadIdx.x;
    if (bid < 512) {
        __shared__ float srow[512];
        srow[tid] = cW[(size_t)bid * 512 + tid];
        srow[256 + tid] = cW[(size_t)bid * 512 + 256 + tid];
        __syncthreads();
#pragma unroll
        for (int rep = 0; rep < 4; rep++) {
            int col = rep * 256 + tid;
            float a = 0.f;
#pragma unroll 4
            for (int c = 0; c < 512; c++) a += srow[c] * wWx[(size_t)c * 1024 + col];
            WfT[(size_t)col * 768 + bid] = a;   // transposed store
        }
    } else if (bid < 516) {
        int col = (bid - 512) * 256 + tid;
        float a = wb[col];
#pragma unroll 4
        for (int c = 0; c < 512; c++) a += cb[c] * wWx[(size_t)c * 1024 + col];
        bfv[col] = a;
    } else if (bid < 644) {
        int k0 = (bid - 516) * 2;
        for (int kk = k0; kk < k0 + 2; kk++)
            for (int col = tid; col < 1024; col += 256)
                rWT[(size_t)col * 512 + kk] = rWx[(size_t)kk * 1024 + col];
    } else if (bid < 772) {
        int k0 = (bid - 644) * 2;
        for (int kk = k0; kk < k0 + 2; kk++)
            for (int col = tid; col < 1024; col += 256)
                rWT[(size_t)col * 512 + 256 + kk] = rWh[(size_t)kk * 1024 + col];
    } else if (bid < 900) {
        int k0 = (bid - 772) * 2;
        for (int kk = k0; kk < k0 + 2; kk++)
            for (int col = tid; col < 1024; col += 256)
                WfT[(size_t)col * 768 + 512 + kk] = wWh[(size_t)kk * 1024 + col];
    }
}

// ---------------- reader LSTM for one step: 8 b (wave=b) x 4 j per block ----------------
__device__ __forceinline__ void reader_step(
    int t1, int bg, int j0, int w, int ln, int tid,
    const float* __restrict__ x, const float* __restrict__ rWT,
    const float* __restrict__ rb,
    const float* __restrict__ hr_in, const float* __restrict__ cr_in,
    float* __restrict__ hr_out, float* __restrict__ cr_out,
    float* __restrict__ sh, bool first) {
    // stage inputs [8][512] = [x_t1 | hr_in] per b
#pragma unroll
    for (int j = 0; j < 2; j++) {
        int i4 = tid + j * 512;
        int bl = i4 >> 7, kq = i4 & 127;
        int b = bg * 8 + bl;
        float4 v;
        if (kq < 64) {
            v = ((const float4*)(x + ((size_t)b * LL + t1) * KK))[kq];
        } else if (!first) {
            v = ((const float4*)(hr_in + b * KK))[kq - 64];
        } else {
            v = make_float4(0.f, 0.f, 0.f, 0.f);
        }
        ((float4*)(sh + bl * 512))[kq] = v;
    }
    __syncthreads();
    int jq = ln & 3, gate = (ln >> 2) & 3, ks = ln >> 4;
    int col = gate * KK + j0 + jq;
    float acc = (ks == 0) ? rb[col] : 0.f;
    const float4* wp = (const float4*)(rWT + (size_t)col * 512) + ks * 32;
    const float4* ip = (const float4*)(sh + w * 512) + ks * 32;
#pragma unroll 8
    for (int i = 0; i < 32; i++) {
        float4 a = ip[i], q = wp[i];
        acc += a.x * q.x + a.y * q.y + a.z * q.z + a.w * q.w;
    }
    acc += __shfl_xor(acc, 16);
    acc += __shfl_xor(acc, 32);
    int jl = ln & 3;
    float gi = __shfl(acc, jl);
    float gf = __shfl(acc, 4 + jl);
    float gG = __shfl(acc, 8 + jl);
    float go = __shfl(acc, 12 + jl);
    if (ln < 4) {
        int b = bg * 8 + w, jj = j0 + ln;
        float cp = first ? 0.f : cr_in[b * KK + jj];
        float cn = sigf(gf) * cp + sigf(gi) * tanhf(gG);
        float hn = sigf(go) * tanhf(cn);
        cr_out[b * KK + jj] = cn;
        hr_out[b * KK + jj] = hn;
    }
}

// ---------------- persistent cooperative kernel ----------------
__global__ __launch_bounds__(512, 2) void k_nse(
    const float* __restrict__ x, const float* __restrict__ rb,
    const float* __restrict__ rWT, const float* __restrict__ WfT,
    const float* __restrict__ bfv, float* __restrict__ st,
    float* __restrict__ out) {
    __shared__ float smem[32768 + 6144 + 64];
    float* memT = smem;           // [128][256] mem tile
    float* sh = smem + 32768;     // phase-A combine scratch / phase-B inputs (aliased)

    float* hrb[2] = { st, st + 8192 };
    float* crb[2] = { st + 16384, st + 24576 };
    float* hwb[2] = { st + 32768, st + 40960 };
    float* cwb[2] = { st + 49152, st + 57344 };
    float* Mf = st + 65536;        // 32
    float* Sf = Mf + 32;           // 32
    float* partM = Sf + 32;        // 256
    float* partS = partM + 256;    // 256
    float* partV = partS + 256;    // 256*256

    cg::grid_group grid = cg::this_grid();
    int g = blockIdx.x, tid = threadIdx.x;
    int w = tid >> 6, ln = tid & 63;
    int bA = g >> 3;                      // phase A batch
    int bg = g >> 6, j0 = (g & 63) * 4;   // phase B roles

    // prologue: mem tile <- x ; reader step 0 (zero states)
    const float4* xsrc = (const float4*)(x + ((size_t)bA * LL + (size_t)(g & 7) * 128) * KK);
#pragma unroll
    for (int i = 0; i < 16; i++) ((float4*)memT)[tid + i * 512] = xsrc[tid + i * 512];
    reader_step(0, bg, j0, w, ln, tid, x, rWT, rb, hrb[0], crb[0], hrb[0], crb[0], sh, true);
    grid.sync();

    float sprev[16];
    for (int t = 0; t < LL; t++) {
        int cur = t & 1, prv = cur ^ 1;
        // ===== phase A: deferred mem update + scores + online softmax partials =====
        float4 h4 = ((const float4*)(hrb[cur] + bA * KK))[ln];
        float4 w4 = make_float4(0.f, 0.f, 0.f, 0.f);
        float Mprev = 0.f, invS = 0.f;
        if (t > 0) {
            w4 = ((const float4*)(hwb[prv] + bA * KK))[ln];
            Mprev = Mf[bA];
            invS = 1.0f / Sf[bA];
        }
        float Mw = -INFINITY, Sw = 0.f;
        float4 Vw = make_float4(0.f, 0.f, 0.f, 0.f);
        float* rowp = memT + w * 16 * KK;
#pragma unroll
        for (int i = 0; i < 16; i++) {
            float4* vp = (float4*)(rowp + i * KK) + ln;
            float4 v = *vp;
            if (t > 0) {
                float z = __expf(sprev[i] - Mprev) * invS;
                float om = 1.0f - z;
                v.x = v.x * om + w4.x * z;
                v.y = v.y * om + w4.y * z;
                v.z = v.z * om + w4.z * z;
                v.w = v.w * om + w4.w * z;
                *vp = v;
            }
            float d = h4.x * v.x + h4.y * v.y + h4.z * v.z + h4.w * v.w;
#pragma unroll
            for (int m = 1; m < 64; m <<= 1) d += __shfl_xor(d, m);
            sprev[i] = d;
            float nM = fmaxf(Mw, d);
            float sc = __expf(Mw - nM);
            float e = __expf(d - nM);
            Sw = Sw * sc + e;
            Vw.x = Vw.x * sc + e * v.x;
            Vw.y = Vw.y * sc + e * v.y;
            Vw.z = Vw.z * sc + e * v.z;
            Vw.w = Vw.w * sc + e * v.w;
            Mw = nM;
        }
        // block-combine 8 wave partials
        float* sV = sh;                 // [8][256]
        float* sM8 = sh + 2048;
        float* sS8 = sM8 + 8;
        ((float4*)(sV + w * KK))[ln] = Vw;
        if (ln == 0) { sM8[w] = Mw; sS8[w] = Sw; }
        __syncthreads();
        if (tid < 256) {
            float M = sM8[0];
#pragma unroll
            for (int q = 1; q < 8; q++) M = fmaxf(M, sM8[q]);
            float S = 0.f, V = 0.f;
#pragma unroll
            for (int q = 0; q < 8; q++) {
                float e = __expf(sM8[q] - M);
                S += e * sS8[q];
                V += e * sV[q * KK + tid];
            }
            partV[g * KK + tid] = V;
            if (tid == 0) { partM[g] = M; partS[g] = S; }
        }
        grid.sync();

        // ===== phase B: softmax finalize + writer LSTM + reader t+1 =====
        {
            int b = bg * 8 + w;
            float pm[8], ps[8];
#pragma unroll
            for (int q = 0; q < 8; q++) { pm[q] = partM[b * 8 + q]; ps[q] = partS[b * 8 + q]; }
            float M = pm[0];
#pragma unroll
            for (int q = 1; q < 8; q++) M = fmaxf(M, pm[q]);
            float S = 0.f;
            float4 V = make_float4(0.f, 0.f, 0.f, 0.f);
#pragma unroll
            for (int q = 0; q < 8; q++) {
                float e = __expf(pm[q] - M);
                S += e * ps[q];
                float4 pv = ((const float4*)(partV + (b * 8 + q) * KK))[ln];
                V.x += e * pv.x; V.y += e * pv.y; V.z += e * pv.z; V.w += e * pv.w;
            }
            float rS = 1.0f / S;
            float* shb = sh + w * 768;   // [hr | m_rt | hw_prev]
            ((float4*)shb)[ln] = ((const float4*)(hrb[cur] + b * KK))[ln];
            ((float4*)(shb + 256))[ln] = make_float4(V.x * rS, V.y * rS, V.z * rS, V.w * rS);
            float4 hwp = make_float4(0.f, 0.f, 0.f, 0.f);
            if (t > 0) hwp = ((const float4*)(hwb[prv] + b * KK))[ln];
            ((float4*)(shb + 512))[ln] = hwp;
            if ((g & 63) == 0 && ln == 0) { Mf[b] = M; Sf[b] = S; }
            __syncthreads();
            // writer matvec: 768 rows x (4 gates x 4 j), 4-way k-split in-wave
            int jq = ln & 3, gate = (ln >> 2) & 3, ks = ln >> 4;
            int col = gate * KK + j0 + jq;
            float acc = (ks == 0) ? bfv[col] : 0.f;
            const float4* wp = (const float4*)(WfT + (size_t)col * 768) + ks * 48;
            const float4* ip = (const float4*)shb + ks * 48;
#pragma unroll 8
            for (int i = 0; i < 48; i++) {
                float4 a = ip[i], q = wp[i];
                acc += a.x * q.x + a.y * q.y + a.z * q.z + a.w * q.w;
            }
            acc += __shfl_xor(acc, 16);
            acc += __shfl_xor(acc, 32);
            int jl = ln & 3;
            float gi = __shfl(acc, jl);
            float gf = __shfl(acc, 4 + jl);
            float gG = __shfl(acc, 8 + jl);
            float go = __shfl(acc, 12 + jl);
            if (ln < 4) {
                int jj = j0 + ln;
                float cp = (t > 0) ? cwb[prv][b * KK + jj] : 0.f;
                float cn = sigf(gf) * cp + sigf(gi) * tanhf(gG);
                float hn = sigf(go) * tanhf(cn);
                cwb[cur][b * KK + jj] = cn;
                hwb[cur][b * KK + jj] = hn;
                out[((size_t)b * LL + t) * KK + jj] = hn;
            }
            // reader for t+1 (overwrites sh; writer reads are done)
            if (t + 1 < LL) {
                __syncthreads();
                reader_step(t + 1, bg, j0, w, ln, tid, x, rWT, rb,
                            hrb[cur], crb[cur], hrb[prv], crb[prv], sh, false);
            }
        }
        grid.sync();
    }
}

// ---------------- host ----------------
extern "C" void kernel_launch(void* const* d_in, const int* in_sizes, int n_in,
                              void* d_out, int out_size, void* d_ws, size_t ws_size,
                              hipStream_t stream) {
    const float* x   = (const float*)d_in[0];
    const float* rWx = (const float*)d_in[1];
    const float* rWh = (const float*)d_in[2];
    const float* rb  = (const float*)d_in[3];
    const float* wWx = (const float*)d_in[4];
    const float* wWh = (const float*)d_in[5];
    const float* wb  = (const float*)d_in[6];
    const float* cW  = (const float*)d_in[7];
    const float* cb  = (const float*)d_in[8];
    float* out = (float*)d_out;

    float* ws = (float*)d_ws;
    float* WfT = ws;                        // 1024*768
    float* rWT = ws + 786432;               // 1024*512
    float* bfv = ws + 786432 + 524288;      // 1024
    float* st  = bfv + 1024;                // states + partials (131648 floats)

    k_pre<<<900, 256, 0, stream>>>(cW, cb, wWx, wb, rWx, rWh, wWh, WfT, rWT, bfv);

    const float* a_x = x; const float* a_rb = rb;
    const float* a_rWT = rWT; const float* a_WfT = WfT; const float* a_bf = bfv;
    float* a_st = st; float* a_out = out;
    void* args[] = { &a_x, &a_rb, &a_rWT, &a_WfT, &a_bf, &a_st, &a_out };
    hipLaunchCooperativeKernel(reinterpret_cast<void*>(k_nse), dim3(256), dim3(512),
                               args, 0, stream);
}

// Round 2
// 42513.596 us; speedup vs baseline: 2.0758x; 2.0758x over previous
//
#include <hip/hip_runtime.h>
#include <math.h>

// NSE recurrent model, B=32, L=1024, K=256 — persistent kernel, custom group barriers.
// mem (32MB) lives in aggregate LDS: 256 blocks x 128 rows x 1KB.
// Groups of 64 blocks are fully independent (blocks [64g,64g+64) own batch rows [8g,8g+8)):
//   phase A: block g scores+updates mem rows of (b=g>>3, l=(g&7)*128..+128)
//   phase B: block g computes writer+reader gate cols j0=(g&63)*4 for all 8 b of its group.
// Sync = 64-block barrier (monotone counter, agent-scope atomics), 2 per step.
// Reader LSTM for t+1 runs between arrive#1 and wait#1 to hide barrier latency.

#define Bb 32
#define LL 1024
#define KK 256

__device__ __forceinline__ float sigf(float v) { return 1.0f / (1.0f + __expf(-v)); }

// ---------------- group barrier: monotone counter, agent scope ----------------
__device__ __forceinline__ void bar_arrive(unsigned* c) {
    __syncthreads();  // all waves' stores complete (vmcnt drain) before release
    if (threadIdx.x == 0)
        __hip_atomic_fetch_add(c, 1u, __ATOMIC_RELEASE, __HIP_MEMORY_SCOPE_AGENT);
}
__device__ __forceinline__ void bar_wait(unsigned* c, unsigned target) {
    if (threadIdx.x == 0) {
        while (__hip_atomic_load(c, __ATOMIC_RELAXED, __HIP_MEMORY_SCOPE_AGENT) < target)
            __builtin_amdgcn_s_sleep(1);
        __builtin_amdgcn_fence(__ATOMIC_ACQUIRE, "agent");
    }
    __syncthreads();
}

// ---------------- one-time: WfT = [cW@wWx ; wWh]^T (768 per col), bf = cb@wWx + wb,
// ---------------- rWT = [rWx ; rWh]^T (512 per col), zero barrier counters
__global__ __launch_bounds__(256) void k_pre(
    const float* __restrict__ cW, const float* __restrict__ cb,
    const float* __restrict__ wWx, const float* __restrict__ wb,
    const float* __restrict__ rWx, const float* __restrict__ rWh,
    const float* __restrict__ wWh,
    float* __restrict__ WfT, float* __restrict__ rWT, float* __restrict__ bfv,
    unsigned* __restrict__ cnt) {
    int bid = blockIdx.x, tid = threadIdx.x;
    if (bid < 512) {
        __shared__ float srow[512];
        srow[tid] = cW[(size_t)bid * 512 + tid];
        srow[256 + tid] = cW[(size_t)bid * 512 + 256 + tid];
        __syncthreads();
#pragma unroll
        for (int rep = 0; rep < 4; rep++) {
            int col = rep * 256 + tid;
            float a = 0.f;
#pragma unroll 4
            for (int c = 0; c < 512; c++) a += srow[c] * wWx[(size_t)c * 1024 + col];
            WfT[(size_t)col * 768 + bid] = a;   // transposed store
        }
    } else if (bid < 516) {
        int col = (bid - 512) * 256 + tid;
        float a = wb[col];
#pragma unroll 4
        for (int c = 0; c < 512; c++) a += cb[c] * wWx[(size_t)c * 1024 + col];
        bfv[col] = a;
    } else if (bid < 644) {
        int k0 = (bid - 516) * 2;
        for (int kk = k0; kk < k0 + 2; kk++)
            for (int col = tid; col < 1024; col += 256)
                rWT[(size_t)col * 512 + kk] = rWx[(size_t)kk * 1024 + col];
    } else if (bid < 772) {
        int k0 = (bid - 644) * 2;
        for (int kk = k0; kk < k0 + 2; kk++)
            for (int col = tid; col < 1024; col += 256)
                rWT[(size_t)col * 512 + 256 + kk] = rWh[(size_t)kk * 1024 + col];
    } else if (bid < 900) {
        int k0 = (bid - 772) * 2;
        for (int kk = k0; kk < k0 + 2; kk++)
            for (int col = tid; col < 1024; col += 256)
                WfT[(size_t)col * 768 + 512 + kk] = wWh[(size_t)kk * 1024 + col];
    } else {
        if (tid < 16) cnt[tid] = 0u;
    }
}

// ---------------- reader LSTM for one step: 8 b (wave=b) x 4 j per block ----------------
__device__ __forceinline__ void reader_step(
    int t1, int bg, int j0, int w, int ln, int tid,
    const float* __restrict__ x, const float* __restrict__ rWT,
    const float* __restrict__ rb,
    const float* __restrict__ hr_in, const float* __restrict__ cr_in,
    float* __restrict__ hr_out, float* __restrict__ cr_out,
    float* __restrict__ sh, bool first) {
    // stage inputs [8][512] = [x_t1 | hr_in] per b
#pragma unroll
    for (int j = 0; j < 2; j++) {
        int i4 = tid + j * 512;
        int bl = i4 >> 7, kq = i4 & 127;
        int b = bg * 8 + bl;
        float4 v;
        if (kq < 64) {
            v = ((const float4*)(x + ((size_t)b * LL + t1) * KK))[kq];
        } else if (!first) {
            v = ((const float4*)(hr_in + b * KK))[kq - 64];
        } else {
            v = make_float4(0.f, 0.f, 0.f, 0.f);
        }
        ((float4*)(sh + bl * 512))[kq] = v;
    }
    __syncthreads();
    int jq = ln & 3, gate = (ln >> 2) & 3, ks = ln >> 4;
    int col = gate * KK + j0 + jq;
    float acc = (ks == 0) ? rb[col] : 0.f;
    const float4* wp = (const float4*)(rWT + (size_t)col * 512);
    const float4* ip = (const float4*)(sh + w * 512);
#pragma unroll 8
    for (int i = 0; i < 32; i++) {
        int idx = i * 4 + ks;   // interleaved k-split: banks {4ks, 4ks+16}, conflict-free
        float4 a = ip[idx], q = wp[idx];
        acc += a.x * q.x + a.y * q.y + a.z * q.z + a.w * q.w;
    }
    acc += __shfl_xor(acc, 16);
    acc += __shfl_xor(acc, 32);
    int jl = ln & 3;
    float gi = __shfl(acc, jl);
    float gf = __shfl(acc, 4 + jl);
    float gG = __shfl(acc, 8 + jl);
    float go = __shfl(acc, 12 + jl);
    if (ln < 4) {
        int b = bg * 8 + w, jj = j0 + ln;
        float cp = first ? 0.f : cr_in[b * KK + jj];
        float cn = sigf(gf) * cp + sigf(gi) * tanhf(gG);
        float hn = sigf(go) * tanhf(cn);
        cr_out[b * KK + jj] = cn;
        hr_out[b * KK + jj] = hn;
    }
}

// ---------------- persistent kernel ----------------
__global__ __launch_bounds__(512, 2) void k_nse(
    const float* __restrict__ x, const float* __restrict__ rb,
    const float* __restrict__ rWT, const float* __restrict__ WfT,
    const float* __restrict__ bfv, float* __restrict__ st,
    float* __restrict__ out, unsigned* __restrict__ cnt) {
    __shared__ float smem[32768 + 6144 + 64];
    float* memT = smem;           // [128][256] mem tile
    float* sh = smem + 32768;     // phase-A combine scratch / phase-B inputs (aliased)

    float* hrb[2] = { st, st + 8192 };
    float* crb[2] = { st + 16384, st + 24576 };
    float* hwb[2] = { st + 32768, st + 40960 };
    float* cwb[2] = { st + 49152, st + 57344 };
    float* Mf = st + 65536;        // 32
    float* Sf = Mf + 32;           // 32
    float* partM = Sf + 32;        // 256
    float* partS = partM + 256;    // 256
    float* partV = partS + 256;    // 256*256

    int g = blockIdx.x, tid = threadIdx.x;
    int w = tid >> 6, ln = tid & 63;
    int bA = g >> 3;                      // phase A batch
    int bg = g >> 6, j0 = (g & 63) * 4;   // phase B roles
    unsigned* ca = cnt + bg;
    unsigned* cb = cnt + 4 + bg;

    // prologue: mem tile <- x ; reader step 0 (zero states)
    const float4* xsrc = (const float4*)(x + ((size_t)bA * LL + (size_t)(g & 7) * 128) * KK);
#pragma unroll
    for (int i = 0; i < 16; i++) ((float4*)memT)[tid + i * 512] = xsrc[tid + i * 512];
    reader_step(0, bg, j0, w, ln, tid, x, rWT, rb, hrb[0], crb[0], hrb[0], crb[0], sh, true);
    bar_arrive(cb);
    bar_wait(cb, 64u);

    float sprev[16];
    for (int t = 0; t < LL; t++) {
        int cur = t & 1, prv = cur ^ 1;
        // ===== phase A: deferred mem update + scores + online softmax partials =====
        float4 h4 = ((const float4*)(hrb[cur] + bA * KK))[ln];
        float4 w4 = make_float4(0.f, 0.f, 0.f, 0.f);
        float Mprev = 0.f, invS = 0.f;
        if (t > 0) {
            w4 = ((const float4*)(hwb[prv] + bA * KK))[ln];
            Mprev = Mf[bA];
            invS = 1.0f / Sf[bA];
        }
        float Mw = -INFINITY, Sw = 0.f;
        float4 Vw = make_float4(0.f, 0.f, 0.f, 0.f);
        float* rowp = memT + w * 16 * KK;
#pragma unroll
        for (int i = 0; i < 16; i++) {
            float4* vp = (float4*)(rowp + i * KK) + ln;
            float4 v = *vp;
            if (t > 0) {
                float z = __expf(sprev[i] - Mprev) * invS;
                float om = 1.0f - z;
                v.x = v.x * om + w4.x * z;
                v.y = v.y * om + w4.y * z;
                v.z = v.z * om + w4.z * z;
                v.w = v.w * om + w4.w * z;
                *vp = v;
            }
            float d = h4.x * v.x + h4.y * v.y + h4.z * v.z + h4.w * v.w;
#pragma unroll
            for (int m = 1; m < 64; m <<= 1) d += __shfl_xor(d, m);
            sprev[i] = d;
            float nM = fmaxf(Mw, d);
            float sc = __expf(Mw - nM);
            float e = __expf(d - nM);
            Sw = Sw * sc + e;
            Vw.x = Vw.x * sc + e * v.x;
            Vw.y = Vw.y * sc + e * v.y;
            Vw.z = Vw.z * sc + e * v.z;
            Vw.w = Vw.w * sc + e * v.w;
            Mw = nM;
        }
        // block-combine 8 wave partials
        float* sV = sh;                 // [8][256]
        float* sM8 = sh + 2048;
        float* sS8 = sM8 + 8;
        ((float4*)(sV + w * KK))[ln] = Vw;
        if (ln == 0) { sM8[w] = Mw; sS8[w] = Sw; }
        __syncthreads();
        if (tid < 256) {
            float M = sM8[0];
#pragma unroll
            for (int q = 1; q < 8; q++) M = fmaxf(M, sM8[q]);
            float S = 0.f, V = 0.f;
#pragma unroll
            for (int q = 0; q < 8; q++) {
                float e = __expf(sM8[q] - M);
                S += e * sS8[q];
                V += e * sV[q * KK + tid];
            }
            partV[g * KK + tid] = V;
            if (tid == 0) { partM[g] = M; partS[g] = S; }
        }
        bar_arrive(ca);   // release partials to group

        // ===== reader t+1 (independent of phase-A partials): hides barrier latency =====
        if (t + 1 < LL)
            reader_step(t + 1, bg, j0, w, ln, tid, x, rWT, rb,
                        hrb[cur], crb[cur], hrb[prv], crb[prv], sh, false);

        bar_wait(ca, 64u * (unsigned)(t + 1));

        // ===== phase B: softmax finalize + writer LSTM =====
        {
            int b = bg * 8 + w;
            float pm[8], ps[8];
#pragma unroll
            for (int q = 0; q < 8; q++) { pm[q] = partM[b * 8 + q]; ps[q] = partS[b * 8 + q]; }
            float M = pm[0];
#pragma unroll
            for (int q = 1; q < 8; q++) M = fmaxf(M, pm[q]);
            float S = 0.f;
            float4 V = make_float4(0.f, 0.f, 0.f, 0.f);
#pragma unroll
            for (int q = 0; q < 8; q++) {
                float e = __expf(pm[q] - M);
                S += e * ps[q];
                float4 pv = ((const float4*)(partV + (b * 8 + q) * KK))[ln];
                V.x += e * pv.x; V.y += e * pv.y; V.z += e * pv.z; V.w += e * pv.w;
            }
            float rS = 1.0f / S;
            float* shb = sh + w * 768;   // [hr | m_rt | hw_prev]
            ((float4*)shb)[ln] = ((const float4*)(hrb[cur] + b * KK))[ln];
            ((float4*)(shb + 256))[ln] = make_float4(V.x * rS, V.y * rS, V.z * rS, V.w * rS);
            float4 hwp = make_float4(0.f, 0.f, 0.f, 0.f);
            if (t > 0) hwp = ((const float4*)(hwb[prv] + b * KK))[ln];
            ((float4*)(shb + 512))[ln] = hwp;
            if ((g & 63) == 0 && ln == 0) { Mf[b] = M; Sf[b] = S; }
            __syncthreads();
            // writer matvec: 768 rows x (4 gates x 4 j), interleaved 4-way k-split
            int jq = ln & 3, gate = (ln >> 2) & 3, ks = ln >> 4;
            int col = gate * KK + j0 + jq;
            float acc = (ks == 0) ? bfv[col] : 0.f;
            const float4* wp = (const float4*)(WfT + (size_t)col * 768);
            const float4* ip = (const float4*)shb;
#pragma unroll 8
            for (int i = 0; i < 48; i++) {
                int idx = i * 4 + ks;   // banks {4ks, 4ks+16}, conflict-free
                float4 a = ip[idx], q = wp[idx];
                acc += a.x * q.x + a.y * q.y + a.z * q.z + a.w * q.w;
            }
            acc += __shfl_xor(acc, 16);
            acc += __shfl_xor(acc, 32);
            int jl = ln & 3;
            float gi = __shfl(acc, jl);
            float gf = __shfl(acc, 4 + jl);
            float gG = __shfl(acc, 8 + jl);
            float go = __shfl(acc, 12 + jl);
            if (ln < 4) {
                int jj = j0 + ln;
                float cp = (t > 0) ? cwb[prv][b * KK + jj] : 0.f;
                float cn = sigf(gf) * cp + sigf(gi) * tanhf(gG);
                float hn = sigf(go) * tanhf(cn);
                cwb[cur][b * KK + jj] = cn;
                hwb[cur][b * KK + jj] = hn;
                out[((size_t)b * LL + t) * KK + jj] = hn;
            }
        }
        bar_arrive(cb);   // release states to group
        bar_wait(cb, 64u * (unsigned)(t + 2));
    }
}

// ---------------- host ----------------
extern "C" void kernel_launch(void* const* d_in, const int* in_sizes, int n_in,
                              void* d_out, int out_size, void* d_ws, size_t ws_size,
                              hipStream_t stream) {
    const float* x   = (const float*)d_in[0];
    const float* rWx = (const float*)d_in[1];
    const float* rWh = (const float*)d_in[2];
    const float* rb  = (const float*)d_in[3];
    const float* wWx = (const float*)d_in[4];
    const float* wWh = (const float*)d_in[5];
    const float* wb  = (const float*)d_in[6];
    const float* cW  = (const float*)d_in[7];
    const float* cb  = (const float*)d_in[8];
    float* out = (float*)d_out;

    float* ws = (float*)d_ws;
    float* WfT = ws;                        // 1024*768
    float* rWT = ws + 786432;               // 1024*512
    float* bfv = ws + 786432 + 524288;      // 1024
    float* st  = bfv + 1024;                // states + partials (131648 floats)
    unsigned* cnt = (unsigned*)(st + 131648); // 16 barrier counters

    k_pre<<<901, 256, 0, stream>>>(cW, cb, wWx, wb, rWx, rWh, wWh, WfT, rWT, bfv, cnt);

    const float* a_x = x; const float* a_rb = rb;
    const float* a_rWT = rWT; const float* a_WfT = WfT; const float* a_bf = bfv;
    float* a_st = st; float* a_out = out; unsigned* a_cnt = cnt;
    void* args[] = { &a_x, &a_rb, &a_rWT, &a_WfT, &a_bf, &a_st, &a_out, &a_cnt };
    hipLaunchCooperativeKernel(reinterpret_cast<void*>(k_nse), dim3(256), dim3(512),
                               args, 0, stream);
}

// Round 3
// 36235.498 us; speedup vs baseline: 2.4354x; 1.1733x over previous
//
#include <hip/hip_runtime.h>
#include <math.h>

// NSE recurrent model, B=32, L=1024, K=256 — persistent kernel, FENCE-FREE group sync.
// mem (32MB) lives in aggregate LDS: 256 blocks x 128 rows x 1KB.
// Groups of 64 blocks independent (blocks [64g,64g+64) own batch rows [8g,8g+8)):
//   phase A: block g scores+updates mem rows of (b=g>>3, l=(g&7)*128..+128)
//   phase B: block g computes writer gate cols j0=(g&63)*4 for all 8 b of its group.
// All cross-block payload (partials, hr, hw, M/S) moves via relaxed agent-scope 64-bit
// atomics (coherence-point access, no cache invalidates). Barriers = relaxed atomicAdd
// + relaxed spin + explicit vmcnt drain. Weights/x/mem stay cache-resident all 1024 steps.
// cr/cw LSTM cell states are thread-private across steps -> registers, never in memory.

#define Bb 32
#define LL 1024
#define KK 256
#define ASCOPE __HIP_MEMORY_SCOPE_AGENT

__device__ __forceinline__ float sigf(float v) { return 1.0f / (1.0f + __expf(-v)); }

__device__ __forceinline__ void st_coh2(float* p, float a, float b) {
    float2 v = make_float2(a, b);
    __hip_atomic_store((unsigned long long*)p,
                       __builtin_bit_cast(unsigned long long, v),
                       __ATOMIC_RELAXED, ASCOPE);
}
__device__ __forceinline__ float2 ld_coh2(const float* p) {
    unsigned long long u = __hip_atomic_load((const unsigned long long*)p,
                                             __ATOMIC_RELAXED, ASCOPE);
    return __builtin_bit_cast(float2, u);
}

// ---------------- fence-free group barrier ----------------
__device__ __forceinline__ void bar_arrive(unsigned* c) {
    asm volatile("s_waitcnt vmcnt(0) lgkmcnt(0)" ::: "memory");  // drain own stores
    __syncthreads();                                             // all waves drained
    if (threadIdx.x == 0)
        __hip_atomic_fetch_add(c, 1u, __ATOMIC_RELAXED, ASCOPE);
}
__device__ __forceinline__ void bar_wait(unsigned* c, unsigned target) {
    if (threadIdx.x == 0) {
        while (__hip_atomic_load(c, __ATOMIC_RELAXED, ASCOPE) < target)
            __builtin_amdgcn_s_sleep(2);
    }
    asm volatile("" ::: "memory");
    __syncthreads();
}

// ---------------- one-time: WfT = [cW@wWx ; wWh]^T (768/col), bf = cb@wWx + wb,
// ---------------- rWT = [rWx ; rWh]^T (512/col), zero barrier counters
__global__ __launch_bounds__(256) void k_pre(
    const float* __restrict__ cW, const float* __restrict__ cb,
    const float* __restrict__ wWx, const float* __restrict__ wb,
    const float* __restrict__ rWx, const float* __restrict__ rWh,
    const float* __restrict__ wWh,
    float* __restrict__ WfT, float* __restrict__ rWT, float* __restrict__ bfv,
    unsigned* __restrict__ cnt) {
    int bid = blockIdx.x, tid = threadIdx.x;
    if (bid < 512) {
        __shared__ float srow[512];
        srow[tid] = cW[(size_t)bid * 512 + tid];
        srow[256 + tid] = cW[(size_t)bid * 512 + 256 + tid];
        __syncthreads();
#pragma unroll
        for (int rep = 0; rep < 4; rep++) {
            int col = rep * 256 + tid;
            float a = 0.f;
#pragma unroll 4
            for (int c = 0; c < 512; c++) a += srow[c] * wWx[(size_t)c * 1024 + col];
            WfT[(size_t)col * 768 + bid] = a;   // transposed store
        }
    } else if (bid < 516) {
        int col = (bid - 512) * 256 + tid;
        float a = wb[col];
#pragma unroll 4
        for (int c = 0; c < 512; c++) a += cb[c] * wWx[(size_t)c * 1024 + col];
        bfv[col] = a;
    } else if (bid < 644) {
        int k0 = (bid - 516) * 2;
        for (int kk = k0; kk < k0 + 2; kk++)
            for (int col = tid; col < 1024; col += 256)
                rWT[(size_t)col * 512 + kk] = rWx[(size_t)kk * 1024 + col];
    } else if (bid < 772) {
        int k0 = (bid - 644) * 2;
        for (int kk = k0; kk < k0 + 2; kk++)
            for (int col = tid; col < 1024; col += 256)
                rWT[(size_t)col * 512 + 256 + kk] = rWh[(size_t)kk * 1024 + col];
    } else if (bid < 900) {
        int k0 = (bid - 772) * 2;
        for (int kk = k0; kk < k0 + 2; kk++)
            for (int col = tid; col < 1024; col += 256)
                WfT[(size_t)col * 768 + 512 + kk] = wWh[(size_t)kk * 1024 + col];
    } else {
        if (tid < 16) cnt[tid] = 0u;
    }
}

// ---------------- reader LSTM for one step: 8 b (wave=b) x 4 j per block ----------------
// cr state lives in crreg (per-thread, col j0+(ln&3) of b=bg*8+w).
__device__ __forceinline__ void reader_step(
    int t1, int bg, int j0, int w, int ln, int tid,
    const float* __restrict__ x, const float* __restrict__ rWT,
    const float* __restrict__ rb,
    const float* __restrict__ hr_in, float* __restrict__ hr_out,
    float& crreg, float* __restrict__ sh, bool first) {
    // stage inputs [8][512] = [x_t1 | hr_in] per b
#pragma unroll
    for (int j = 0; j < 2; j++) {
        int i4 = tid + j * 512;
        int bl = i4 >> 7, kq = i4 & 127;
        int b = bg * 8 + bl;
        float4 v;
        if (kq < 64) {
            v = ((const float4*)(x + ((size_t)b * LL + t1) * KK))[kq];
        } else if (!first) {
            const float* hp = hr_in + b * KK + (kq - 64) * 4;
            float2 a = ld_coh2(hp), c = ld_coh2(hp + 2);
            v = make_float4(a.x, a.y, c.x, c.y);
        } else {
            v = make_float4(0.f, 0.f, 0.f, 0.f);
        }
        ((float4*)(sh + bl * 512))[kq] = v;
    }
    __syncthreads();
    int jq = ln & 3, gate = (ln >> 2) & 3, ks = ln >> 4;
    int col = gate * KK + j0 + jq;
    float acc = (ks == 0) ? rb[col] : 0.f;
    const float4* wp = (const float4*)(rWT + (size_t)col * 512);
    const float4* ip = (const float4*)(sh + w * 512);
#pragma unroll 8
    for (int i = 0; i < 32; i++) {
        int idx = i * 4 + ks;   // interleaved k-split: conflict-free banks
        float4 a = ip[idx], q = wp[idx];
        acc += a.x * q.x + a.y * q.y + a.z * q.z + a.w * q.w;
    }
    acc += __shfl_xor(acc, 16);
    acc += __shfl_xor(acc, 32);
    int jl = ln & 3;
    float gi = __shfl(acc, jl);
    float gf = __shfl(acc, 4 + jl);
    float gG = __shfl(acc, 8 + jl);
    float go = __shfl(acc, 12 + jl);
    float cp = first ? 0.f : crreg;
    float cn = sigf(gf) * cp + sigf(gi) * tanhf(gG);
    float hn = sigf(go) * tanhf(cn);
    crreg = cn;
    float ha = __shfl(hn, 2 * (ln & 31));      // pair values from lanes 0..3
    float hb = __shfl(hn, 2 * (ln & 31) + 1);
    if (ln < 2) {
        int b = bg * 8 + w;
        st_coh2(hr_out + b * KK + j0 + 2 * ln, ha, hb);
    }
}

// ---------------- persistent kernel ----------------
__global__ __launch_bounds__(512, 1) void k_nse(
    const float* __restrict__ x, const float* __restrict__ rb,
    const float* __restrict__ rWT, const float* __restrict__ WfT,
    const float* __restrict__ bfv, float* __restrict__ st,
    float* __restrict__ out, unsigned* __restrict__ cnt) {
    __shared__ float smem[32768 + 6144 + 64];
    float* memT = smem;           // [128][256] mem tile
    float* sh = smem + 32768;     // phase-A combine / phase-B inputs / reader staging

    float* hrb[2] = { st, st + 8192 };
    float* hwb[2] = { st + 16384, st + 24576 };
    float* MSf    = st + 32768;   // [32][2] (M,S) per b
    float* partMS = st + 32832;   // [256][2]
    float* partV  = st + 33344;   // [256][256]

    int g = blockIdx.x, tid = threadIdx.x;
    int w = tid >> 6, ln = tid & 63;
    int bA = g >> 3;                      // phase A batch
    int bg = g >> 6, j0 = (g & 63) * 4;   // phase B roles
    unsigned* ca = cnt + bg;
    unsigned* cb = cnt + 4 + bg;

    float crreg = 0.f, cwreg = 0.f;       // reader/writer cell states (thread-private)

    // prologue: mem tile <- x ; reader step 0 (zero states)
    const float4* xsrc = (const float4*)(x + ((size_t)bA * LL + (size_t)(g & 7) * 128) * KK);
#pragma unroll
    for (int i = 0; i < 16; i++) ((float4*)memT)[tid + i * 512] = xsrc[tid + i * 512];
    reader_step(0, bg, j0, w, ln, tid, x, rWT, rb, hrb[0], hrb[0], crreg, sh, true);
    bar_arrive(cb);
    bar_wait(cb, 64u);

    float sprev[16];
    for (int t = 0; t < LL; t++) {
        int cur = t & 1, prv = cur ^ 1;
        // ===== phase A: deferred mem update + scores + online softmax partials =====
        const float* hp = hrb[cur] + bA * KK + ln * 4;
        float2 ha = ld_coh2(hp), hc = ld_coh2(hp + 2);
        float4 h4 = make_float4(ha.x, ha.y, hc.x, hc.y);
        float4 w4 = make_float4(0.f, 0.f, 0.f, 0.f);
        float Mprev = 0.f, invS = 0.f;
        if (t > 0) {
            const float* wp0 = hwb[prv] + bA * KK + ln * 4;
            float2 wa = ld_coh2(wp0), wc = ld_coh2(wp0 + 2);
            w4 = make_float4(wa.x, wa.y, wc.x, wc.y);
            float2 ms = ld_coh2(MSf + bA * 2);
            Mprev = ms.x;
            invS = 1.0f / ms.y;
        }
        float Mw = -INFINITY, Sw = 0.f;
        float4 Vw = make_float4(0.f, 0.f, 0.f, 0.f);
        float* rowp = memT + w * 16 * KK;
#pragma unroll
        for (int i = 0; i < 16; i++) {
            float4* vp = (float4*)(rowp + i * KK) + ln;
            float4 v = *vp;
            if (t > 0) {
                float z = __expf(sprev[i] - Mprev) * invS;
                float om = 1.0f - z;
                v.x = v.x * om + w4.x * z;
                v.y = v.y * om + w4.y * z;
                v.z = v.z * om + w4.z * z;
                v.w = v.w * om + w4.w * z;
                *vp = v;
            }
            float d = h4.x * v.x + h4.y * v.y + h4.z * v.z + h4.w * v.w;
#pragma unroll
            for (int m = 1; m < 64; m <<= 1) d += __shfl_xor(d, m);
            sprev[i] = d;
            float nM = fmaxf(Mw, d);
            float sc = __expf(Mw - nM);
            float e = __expf(d - nM);
            Sw = Sw * sc + e;
            Vw.x = Vw.x * sc + e * v.x;
            Vw.y = Vw.y * sc + e * v.y;
            Vw.z = Vw.z * sc + e * v.z;
            Vw.w = Vw.w * sc + e * v.w;
            Mw = nM;
        }
        // block-combine 8 wave partials -> coherence point
        float* sV = sh;                 // [8][256]
        float* sM8 = sh + 2048;
        float* sS8 = sM8 + 8;
        ((float4*)(sV + w * KK))[ln] = Vw;
        if (ln == 0) { sM8[w] = Mw; sS8[w] = Sw; }
        __syncthreads();
        if (tid < 128) {
            float M = sM8[0];
#pragma unroll
            for (int q = 1; q < 8; q++) M = fmaxf(M, sM8[q]);
            float S = 0.f, V0 = 0.f, V1 = 0.f;
#pragma unroll
            for (int q = 0; q < 8; q++) {
                float e = __expf(sM8[q] - M);
                S += e * sS8[q];
                V0 += e * sV[q * KK + 2 * tid];
                V1 += e * sV[q * KK + 2 * tid + 1];
            }
            st_coh2(partV + g * KK + 2 * tid, V0, V1);
            if (tid == 0) st_coh2(partMS + g * 2, M, S);
        }
        bar_arrive(ca);   // release partials to group

        // ===== reader t+1 (independent of partials): hides barrier latency =====
        if (t + 1 < LL)
            reader_step(t + 1, bg, j0, w, ln, tid, x, rWT, rb,
                        hrb[cur], hrb[prv], crreg, sh, false);

        bar_wait(ca, 64u * (unsigned)(t + 1));

        // ===== phase B: softmax finalize + writer LSTM =====
        {
            int b = bg * 8 + w;
            float M = -INFINITY;
            float2 pms[8];
#pragma unroll
            for (int q = 0; q < 8; q++) {
                pms[q] = ld_coh2(partMS + (b * 8 + q) * 2);
                M = fmaxf(M, pms[q].x);
            }
            float S = 0.f;
            float4 V = make_float4(0.f, 0.f, 0.f, 0.f);
#pragma unroll
            for (int q = 0; q < 8; q++) {
                float e = __expf(pms[q].x - M);
                S += e * pms[q].y;
                const float* pv = partV + (size_t)(b * 8 + q) * KK + ln * 4;
                float2 v01 = ld_coh2(pv), v23 = ld_coh2(pv + 2);
                V.x += e * v01.x; V.y += e * v01.y; V.z += e * v23.x; V.w += e * v23.y;
            }
            float rS = 1.0f / S;
            float* shb = sh + w * 768;   // [hr | m_rt | hw_prev]
            {
                const float* hq = hrb[cur] + b * KK + ln * 4;
                float2 a = ld_coh2(hq), c = ld_coh2(hq + 2);
                ((float4*)shb)[ln] = make_float4(a.x, a.y, c.x, c.y);
            }
            ((float4*)(shb + 256))[ln] = make_float4(V.x * rS, V.y * rS, V.z * rS, V.w * rS);
            float4 hwp = make_float4(0.f, 0.f, 0.f, 0.f);
            if (t > 0) {
                const float* hq = hwb[prv] + b * KK + ln * 4;
                float2 a = ld_coh2(hq), c = ld_coh2(hq + 2);
                hwp = make_float4(a.x, a.y, c.x, c.y);
            }
            ((float4*)(shb + 512))[ln] = hwp;
            if ((g & 63) == 0 && ln == 0) st_coh2(MSf + b * 2, M, S);
            __syncthreads();
            // writer matvec: 768 rows x (4 gates x 4 j), interleaved 4-way k-split
            int jq = ln & 3, gate = (ln >> 2) & 3, ks = ln >> 4;
            int col = gate * KK + j0 + jq;
            float acc = (ks == 0) ? bfv[col] : 0.f;
            const float4* wp = (const float4*)(WfT + (size_t)col * 768);
            const float4* ip = (const float4*)shb;
#pragma unroll 8
            for (int i = 0; i < 48; i++) {
                int idx = i * 4 + ks;
                float4 a = ip[idx], q = wp[idx];
                acc += a.x * q.x + a.y * q.y + a.z * q.z + a.w * q.w;
            }
            acc += __shfl_xor(acc, 16);
            acc += __shfl_xor(acc, 32);
            int jl = ln & 3;
            float gi = __shfl(acc, jl);
            float gf = __shfl(acc, 4 + jl);
            float gG = __shfl(acc, 8 + jl);
            float go = __shfl(acc, 12 + jl);
            float cp = (t > 0) ? cwreg : 0.f;
            float cn = sigf(gf) * cp + sigf(gi) * tanhf(gG);
            float hn = sigf(go) * tanhf(cn);
            cwreg = cn;
            float pa = __shfl(hn, 2 * (ln & 31));
            float pb = __shfl(hn, 2 * (ln & 31) + 1);
            if (ln < 2) {
                st_coh2(hwb[cur] + b * KK + j0 + 2 * ln, pa, pb);
                *(float2*)(out + ((size_t)b * LL + t) * KK + j0 + 2 * ln) =
                    make_float2(pa, pb);
            }
        }
        bar_arrive(cb);   // release states to group
        bar_wait(cb, 64u * (unsigned)(t + 2));
    }
}

// ---------------- host ----------------
extern "C" void kernel_launch(void* const* d_in, const int* in_sizes, int n_in,
                              void* d_out, int out_size, void* d_ws, size_t ws_size,
                              hipStream_t stream) {
    const float* x   = (const float*)d_in[0];
    const float* rWx = (const float*)d_in[1];
    const float* rWh = (const float*)d_in[2];
    const float* rb  = (const float*)d_in[3];
    const float* wWx = (const float*)d_in[4];
    const float* wWh = (const float*)d_in[5];
    const float* wb  = (const float*)d_in[6];
    const float* cW  = (const float*)d_in[7];
    const float* cb  = (const float*)d_in[8];
    float* out = (float*)d_out;

    float* ws = (float*)d_ws;
    float* WfT = ws;                        // 1024*768
    float* rWT = ws + 786432;               // 1024*512
    float* bfv = ws + 786432 + 524288;      // 1024
    float* st  = bfv + 1024;                // states + partials (98880 floats)
    unsigned* cnt = (unsigned*)(st + 98880); // 16 barrier counters

    k_pre<<<901, 256, 0, stream>>>(cW, cb, wWx, wb, rWx, rWh, wWh, WfT, rWT, bfv, cnt);

    const float* a_x = x; const float* a_rb = rb;
    const float* a_rWT = rWT; const float* a_WfT = WfT; const float* a_bf = bfv;
    float* a_st = st; float* a_out = out; unsigned* a_cnt = cnt;
    void* args[] = { &a_x, &a_rb, &a_rWT, &a_WfT, &a_bf, &a_st, &a_out, &a_cnt };
    hipLaunchCooperativeKernel(reinterpret_cast<void*>(k_nse), dim3(256), dim3(512),
                               args, 0, stream);
}

// Round 4
// 29736.386 us; speedup vs baseline: 2.9677x; 1.2186x over previous
//
#include <hip/hip_runtime.h>
#include <math.h>

// NSE recurrent model, B=32, L=1024, K=256 — persistent kernel, epoch-flag group sync.
// mem (32MB) lives in aggregate LDS: 256 blocks x 128 rows x 1KB.
// Groups of 64 blocks independent (blocks [64g,64g+64) own batch rows [8g,8g+8)):
//   phase A: block g scores+updates mem rows of (b=g>>3, l=(g&7)*128..+128)
//   phase B: block g computes writer gate cols j0=(g&63)*4 for all 8 b of its group.
// Cross-block payload via relaxed agent-scope 64-bit atomics (MALL, no cache flushes).
// Barrier: per-block epoch FLAG (padded to own cacheline, pure store — no RMW
// serialization); waiter wave polls all 64 flags with ONE vector load (__all).
// Reader LSTM for t+1 runs inside barrier-A's shadow. cr/cw cell states in registers.

#define Bb 32
#define LL 1024
#define KK 256
#define ASCOPE __HIP_MEMORY_SCOPE_AGENT
#define FSTR 16   // flag stride in dwords (64B cacheline)

__device__ __forceinline__ float sigf(float v) { return 1.0f / (1.0f + __expf(-v)); }

__device__ __forceinline__ void st_coh2(float* p, float a, float b) {
    float2 v = make_float2(a, b);
    __hip_atomic_store((unsigned long long*)p,
                       __builtin_bit_cast(unsigned long long, v),
                       __ATOMIC_RELAXED, ASCOPE);
}
__device__ __forceinline__ float2 ld_coh2(const float* p) {
    unsigned long long u = __hip_atomic_load((const unsigned long long*)p,
                                             __ATOMIC_RELAXED, ASCOPE);
    return __builtin_bit_cast(float2, u);
}

// ---------------- epoch-flag group barrier (no RMW) ----------------
__device__ __forceinline__ void bar_arrive(unsigned* fown, unsigned val) {
    asm volatile("s_waitcnt vmcnt(0) lgkmcnt(0)" ::: "memory");  // payload drained
    __syncthreads();                                             // all waves drained
    if (threadIdx.x == 0)
        __hip_atomic_store(fown, val, __ATOMIC_RELAXED, ASCOPE);
}
__device__ __forceinline__ void bar_wait(unsigned* fbase, unsigned val) {
    if (threadIdx.x < 64) {   // wave 0: lane ln polls flag ln — one load per round
        for (;;) {
            unsigned v = __hip_atomic_load(fbase + threadIdx.x * FSTR,
                                           __ATOMIC_RELAXED, ASCOPE);
            if (__all(v >= val)) break;
            __builtin_amdgcn_s_sleep(1);
        }
    }
    asm volatile("" ::: "memory");
    __syncthreads();
}

// ---------------- one-time: WfT = [cW@wWx ; wWh]^T (768/col), bf = cb@wWx + wb,
// ---------------- rWT = [rWx ; rWh]^T (512/col), zero epoch flags
__global__ __launch_bounds__(256) void k_pre(
    const float* __restrict__ cW, const float* __restrict__ cb,
    const float* __restrict__ wWx, const float* __restrict__ wb,
    const float* __restrict__ rWx, const float* __restrict__ rWh,
    const float* __restrict__ wWh,
    float* __restrict__ WfT, float* __restrict__ rWT, float* __restrict__ bfv,
    unsigned* __restrict__ flg) {
    int bid = blockIdx.x, tid = threadIdx.x;
    if (bid < 512) {
        __shared__ float srow[512];
        srow[tid] = cW[(size_t)bid * 512 + tid];
        srow[256 + tid] = cW[(size_t)bid * 512 + 256 + tid];
        __syncthreads();
#pragma unroll
        for (int rep = 0; rep < 4; rep++) {
            int col = rep * 256 + tid;
            float a = 0.f;
#pragma unroll 4
            for (int c = 0; c < 512; c++) a += srow[c] * wWx[(size_t)c * 1024 + col];
            WfT[(size_t)col * 768 + bid] = a;   // transposed store
        }
    } else if (bid < 516) {
        int col = (bid - 512) * 256 + tid;
        float a = wb[col];
#pragma unroll 4
        for (int c = 0; c < 512; c++) a += cb[c] * wWx[(size_t)c * 1024 + col];
        bfv[col] = a;
    } else if (bid < 644) {
        int k0 = (bid - 516) * 2;
        for (int kk = k0; kk < k0 + 2; kk++)
            for (int col = tid; col < 1024; col += 256)
                rWT[(size_t)col * 512 + kk] = rWx[(size_t)kk * 1024 + col];
    } else if (bid < 772) {
        int k0 = (bid - 644) * 2;
        for (int kk = k0; kk < k0 + 2; kk++)
            for (int col = tid; col < 1024; col += 256)
                rWT[(size_t)col * 512 + 256 + kk] = rWh[(size_t)kk * 1024 + col];
    } else if (bid < 900) {
        int k0 = (bid - 772) * 2;
        for (int kk = k0; kk < k0 + 2; kk++)
            for (int col = tid; col < 1024; col += 256)
                WfT[(size_t)col * 768 + 512 + kk] = wWh[(size_t)kk * 1024 + col];
    } else {
        int idx = (bid - 900) * 256 + tid;   // 32 blocks x 256 = 8192 flag dwords
        flg[idx] = 0u;
    }
}

// ---------------- reader LSTM for one step: 8 b (wave=b) x 4 j per block ----------------
// cr state lives in crreg (per-thread, col j0+(ln&3) of b=bg*8+w).
__device__ __forceinline__ void reader_step(
    int t1, int bg, int j0, int w, int ln, int tid,
    const float* __restrict__ x, const float* __restrict__ rWT,
    const float* __restrict__ rb,
    const float* __restrict__ hr_in, float* __restrict__ hr_out,
    float& crreg, float* __restrict__ sh, bool first) {
    // stage inputs [8][512] = [x_t1 | hr_in] per b
#pragma unroll
    for (int j = 0; j < 2; j++) {
        int i4 = tid + j * 512;
        int bl = i4 >> 7, kq = i4 & 127;
        int b = bg * 8 + bl;
        float4 v;
        if (kq < 64) {
            v = ((const float4*)(x + ((size_t)b * LL + t1) * KK))[kq];
        } else if (!first) {
            const float* hp = hr_in + b * KK + (kq - 64) * 4;
            float2 a = ld_coh2(hp), c = ld_coh2(hp + 2);
            v = make_float4(a.x, a.y, c.x, c.y);
        } else {
            v = make_float4(0.f, 0.f, 0.f, 0.f);
        }
        ((float4*)(sh + bl * 512))[kq] = v;
    }
    __syncthreads();
    int jq = ln & 3, gate = (ln >> 2) & 3, ks = ln >> 4;
    int col = gate * KK + j0 + jq;
    float acc = (ks == 0) ? rb[col] : 0.f;
    const float4* wp = (const float4*)(rWT + (size_t)col * 512);
    const float4* ip = (const float4*)(sh + w * 512);
#pragma unroll 8
    for (int i = 0; i < 32; i++) {
        int idx = i * 4 + ks;   // interleaved k-split: conflict-free banks
        float4 a = ip[idx], q = wp[idx];
        acc += a.x * q.x + a.y * q.y + a.z * q.z + a.w * q.w;
    }
    acc += __shfl_xor(acc, 16);
    acc += __shfl_xor(acc, 32);
    int jl = ln & 3;
    float gi = __shfl(acc, jl);
    float gf = __shfl(acc, 4 + jl);
    float gG = __shfl(acc, 8 + jl);
    float go = __shfl(acc, 12 + jl);
    float cp = first ? 0.f : crreg;
    float cn = sigf(gf) * cp + sigf(gi) * tanhf(gG);
    float hn = sigf(go) * tanhf(cn);
    crreg = cn;
    float ha = __shfl(hn, 2 * (ln & 31));      // pair values from lanes 0..3
    float hb = __shfl(hn, 2 * (ln & 31) + 1);
    if (ln < 2) {
        int b = bg * 8 + w;
        st_coh2(hr_out + b * KK + j0 + 2 * ln, ha, hb);
    }
}

// ---------------- persistent kernel ----------------
__global__ __launch_bounds__(512, 1) void k_nse(
    const float* __restrict__ x, const float* __restrict__ rb,
    const float* __restrict__ rWT, const float* __restrict__ WfT,
    const float* __restrict__ bfv, float* __restrict__ st,
    float* __restrict__ out, unsigned* __restrict__ flg) {
    __shared__ float smem[32768 + 6144 + 64];
    float* memT = smem;           // [128][256] mem tile
    float* sh = smem + 32768;     // phase-A combine / phase-B inputs / reader staging

    float* hrb[2] = { st, st + 8192 };
    float* hwb[2] = { st + 16384, st + 24576 };
    float* MSf    = st + 32768;   // [32][2] (M,S) per b
    float* partMS = st + 32832;   // [256][2]
    float* partV  = st + 33344;   // [256][256]

    int g = blockIdx.x, tid = threadIdx.x;
    int w = tid >> 6, ln = tid & 63;
    int bA = g >> 3;                      // phase A batch
    int bg = g >> 6, gl = g & 63;         // group, lane-in-group
    int j0 = gl * 4;                      // phase B cols
    unsigned* fA = flg + (bg * 64) * FSTR;          // group A flags
    unsigned* fB = flg + (4 * 64 + bg * 64) * FSTR; // group B flags
    unsigned* fAo = fA + gl * FSTR;
    unsigned* fBo = fB + gl * FSTR;

    float crreg = 0.f, cwreg = 0.f;       // reader/writer cell states (thread-private)

    // prologue: mem tile <- x ; reader step 0 (zero states)
    const float4* xsrc = (const float4*)(x + ((size_t)bA * LL + (size_t)(g & 7) * 128) * KK);
#pragma unroll
    for (int i = 0; i < 16; i++) ((float4*)memT)[tid + i * 512] = xsrc[tid + i * 512];
    reader_step(0, bg, j0, w, ln, tid, x, rWT, rb, hrb[0], hrb[0], crreg, sh, true);
    bar_arrive(fBo, 1u);
    bar_wait(fB, 1u);

    float sprev[16];
    for (int t = 0; t < LL; t++) {
        int cur = t & 1, prv = cur ^ 1;
        // ===== phase A: deferred mem update + scores + online softmax partials =====
        const float* hp = hrb[cur] + bA * KK + ln * 4;
        float2 ha = ld_coh2(hp), hc = ld_coh2(hp + 2);
        float4 h4 = make_float4(ha.x, ha.y, hc.x, hc.y);
        float4 w4 = make_float4(0.f, 0.f, 0.f, 0.f);
        float Mprev = 0.f, invS = 0.f;
        if (t > 0) {
            const float* wp0 = hwb[prv] + bA * KK + ln * 4;
            float2 wa = ld_coh2(wp0), wc = ld_coh2(wp0 + 2);
            w4 = make_float4(wa.x, wa.y, wc.x, wc.y);
            float2 ms = ld_coh2(MSf + bA * 2);
            Mprev = ms.x;
            invS = 1.0f / ms.y;
        }
        float Mw = -INFINITY, Sw = 0.f;
        float4 Vw = make_float4(0.f, 0.f, 0.f, 0.f);
        float* rowp = memT + w * 16 * KK;
#pragma unroll
        for (int i = 0; i < 16; i++) {
            float4* vp = (float4*)(rowp + i * KK) + ln;
            float4 v = *vp;
            if (t > 0) {
                float z = __expf(sprev[i] - Mprev) * invS;
                float om = 1.0f - z;
                v.x = v.x * om + w4.x * z;
                v.y = v.y * om + w4.y * z;
                v.z = v.z * om + w4.z * z;
                v.w = v.w * om + w4.w * z;
                *vp = v;
            }
            float d = h4.x * v.x + h4.y * v.y + h4.z * v.z + h4.w * v.w;
#pragma unroll
            for (int m = 1; m < 64; m <<= 1) d += __shfl_xor(d, m);
            sprev[i] = d;
            float nM = fmaxf(Mw, d);
            float sc = __expf(Mw - nM);
            float e = __expf(d - nM);
            Sw = Sw * sc + e;
            Vw.x = Vw.x * sc + e * v.x;
            Vw.y = Vw.y * sc + e * v.y;
            Vw.z = Vw.z * sc + e * v.z;
            Vw.w = Vw.w * sc + e * v.w;
            Mw = nM;
        }
        // block-combine 8 wave partials -> coherence point
        float* sV = sh;                 // [8][256]
        float* sM8 = sh + 2048;
        float* sS8 = sM8 + 8;
        ((float4*)(sV + w * KK))[ln] = Vw;
        if (ln == 0) { sM8[w] = Mw; sS8[w] = Sw; }
        __syncthreads();
        if (tid < 128) {
            float M = sM8[0];
#pragma unroll
            for (int q = 1; q < 8; q++) M = fmaxf(M, sM8[q]);
            float S = 0.f, V0 = 0.f, V1 = 0.f;
#pragma unroll
            for (int q = 0; q < 8; q++) {
                float e = __expf(sM8[q] - M);
                S += e * sS8[q];
                V0 += e * sV[q * KK + 2 * tid];
                V1 += e * sV[q * KK + 2 * tid + 1];
            }
            st_coh2(partV + g * KK + 2 * tid, V0, V1);
            if (tid == 0) st_coh2(partMS + g * 2, M, S);
        }
        bar_arrive(fAo, (unsigned)(t + 1));   // release partials to group

        // ===== reader t+1 (independent of partials): hides barrier latency =====
        if (t + 1 < LL)
            reader_step(t + 1, bg, j0, w, ln, tid, x, rWT, rb,
                        hrb[cur], hrb[prv], crreg, sh, false);

        bar_wait(fA, (unsigned)(t + 1));

        // ===== phase B: softmax finalize + writer LSTM =====
        {
            int b = bg * 8 + w;
            float M = -INFINITY;
            float2 pms[8];
#pragma unroll
            for (int q = 0; q < 8; q++) {
                pms[q] = ld_coh2(partMS + (b * 8 + q) * 2);
                M = fmaxf(M, pms[q].x);
            }
            float S = 0.f;
            float4 V = make_float4(0.f, 0.f, 0.f, 0.f);
#pragma unroll
            for (int q = 0; q < 8; q++) {
                float e = __expf(pms[q].x - M);
                S += e * pms[q].y;
                const float* pv = partV + (size_t)(b * 8 + q) * KK + ln * 4;
                float2 v01 = ld_coh2(pv), v23 = ld_coh2(pv + 2);
                V.x += e * v01.x; V.y += e * v01.y; V.z += e * v23.x; V.w += e * v23.y;
            }
            float rS = 1.0f / S;
            float* shb = sh + w * 768;   // [hr | m_rt | hw_prev]
            {
                const float* hq = hrb[cur] + b * KK + ln * 4;
                float2 a = ld_coh2(hq), c = ld_coh2(hq + 2);
                ((float4*)shb)[ln] = make_float4(a.x, a.y, c.x, c.y);
            }
            ((float4*)(shb + 256))[ln] = make_float4(V.x * rS, V.y * rS, V.z * rS, V.w * rS);
            float4 hwp = make_float4(0.f, 0.f, 0.f, 0.f);
            if (t > 0) {
                const float* hq = hwb[prv] + b * KK + ln * 4;
                float2 a = ld_coh2(hq), c = ld_coh2(hq + 2);
                hwp = make_float4(a.x, a.y, c.x, c.y);
            }
            ((float4*)(shb + 512))[ln] = hwp;
            if (gl == 0 && ln == 0) st_coh2(MSf + b * 2, M, S);
            __syncthreads();
            // writer matvec: 768 rows x (4 gates x 4 j), interleaved 4-way k-split
            int jq = ln & 3, gate = (ln >> 2) & 3, ks = ln >> 4;
            int col = gate * KK + j0 + jq;
            float acc = (ks == 0) ? bfv[col] : 0.f;
            const float4* wp = (const float4*)(WfT + (size_t)col * 768);
            const float4* ip = (const float4*)shb;
#pragma unroll 8
            for (int i = 0; i < 48; i++) {
                int idx = i * 4 + ks;
                float4 a = ip[idx], q = wp[idx];
                acc += a.x * q.x + a.y * q.y + a.z * q.z + a.w * q.w;
            }
            acc += __shfl_xor(acc, 16);
            acc += __shfl_xor(acc, 32);
            int jl = ln & 3;
            float gi = __shfl(acc, jl);
            float gf = __shfl(acc, 4 + jl);
            float gG = __shfl(acc, 8 + jl);
            float go = __shfl(acc, 12 + jl);
            float cp = (t > 0) ? cwreg : 0.f;
            float cn = sigf(gf) * cp + sigf(gi) * tanhf(gG);
            float hn = sigf(go) * tanhf(cn);
            cwreg = cn;
            float pa = __shfl(hn, 2 * (ln & 31));
            float pb = __shfl(hn, 2 * (ln & 31) + 1);
            if (ln < 2) {
                st_coh2(hwb[cur] + b * KK + j0 + 2 * ln, pa, pb);
                *(float2*)(out + ((size_t)b * LL + t) * KK + j0 + 2 * ln) =
                    make_float2(pa, pb);
            }
        }
        bar_arrive(fBo, (unsigned)(t + 2));   // release states to group
        bar_wait(fB, (unsigned)(t + 2));
    }
}

// ---------------- host ----------------
extern "C" void kernel_launch(void* const* d_in, const int* in_sizes, int n_in,
                              void* d_out, int out_size, void* d_ws, size_t ws_size,
                              hipStream_t stream) {
    const float* x   = (const float*)d_in[0];
    const float* rWx = (const float*)d_in[1];
    const float* rWh = (const float*)d_in[2];
    const float* rb  = (const float*)d_in[3];
    const float* wWx = (const float*)d_in[4];
    const float* wWh = (const float*)d_in[5];
    const float* wb  = (const float*)d_in[6];
    const float* cW  = (const float*)d_in[7];
    const float* cb  = (const float*)d_in[8];
    float* out = (float*)d_out;

    float* ws = (float*)d_ws;
    float* WfT = ws;                        // 1024*768
    float* rWT = ws + 786432;               // 1024*512
    float* bfv = ws + 786432 + 524288;      // 1024
    float* st  = bfv + 1024;                // states + partials (98880 floats)
    unsigned* flg = (unsigned*)(st + 98880); // 2*4*64 flags, 16-dword stride = 8192 u32

    k_pre<<<932, 256, 0, stream>>>(cW, cb, wWx, wb, rWx, rWh, wWh, WfT, rWT, bfv, flg);

    const float* a_x = x; const float* a_rb = rb;
    const float* a_rWT = rWT; const float* a_WfT = WfT; const float* a_bf = bfv;
    float* a_st = st; float* a_out = out; unsigned* a_flg = flg;
    void* args[] = { &a_x, &a_rb, &a_rWT, &a_WfT, &a_bf, &a_st, &a_out, &a_flg };
    hipLaunchCooperativeKernel(reinterpret_cast<void*>(k_nse), dim3(256), dim3(512),
                               args, 0, stream);
}

// Round 6
// 26590.466 us; speedup vs baseline: 3.3188x; 1.1183x over previous
//
#include <hip/hip_runtime.h>
#include <math.h>

// NSE recurrent model, B=32, L=1024, K=256 — persistent kernel, R5 (resubmit).
// mem (32MB) in aggregate LDS: 256 blocks x 128 rows x 1KB.
// Groups of 64 blocks (batch rows [8g,8g+8)). Per step:
//   phase A (de-chained): batched dots + pipelined butterfly + 2-pass softmax partials
//   arrive A -> shadow: stage [x_{t+1}|hr_t|hw_{t-1}]; writer-PRE (hr,hw rows, L2);
//               reader t+1 (L2) — all off the critical path
//   per-WAVE waitA on 8 producer flags -> B-post: m_rt combine + m_rt@Wf2 with Wf2
//               REGISTER-resident (16 float4/thread) -> LSTM pointwise -> hw, out
//   arrive B -> block waitB.
// Payload via relaxed agent-scope 64b atomics (MALL). cr/cw cell states in registers.

#define Bb 32
#define LL 1024
#define KK 256
#define ASCOPE __HIP_MEMORY_SCOPE_AGENT
#define FSTR 16   // flag stride in dwords (64B line)

__device__ __forceinline__ float sigf(float v) { return 1.0f / (1.0f + __expf(-v)); }

__device__ __forceinline__ void st_coh2(float* p, float a, float b) {
    float2 v = make_float2(a, b);
    __hip_atomic_store((unsigned long long*)p,
                       __builtin_bit_cast(unsigned long long, v),
                       __ATOMIC_RELAXED, ASCOPE);
}
__device__ __forceinline__ float2 ld_coh2(const float* p) {
    unsigned long long u = __hip_atomic_load((const unsigned long long*)p,
                                             __ATOMIC_RELAXED, ASCOPE);
    return __builtin_bit_cast(float2, u);
}

__device__ __forceinline__ void bar_arrive(unsigned* fown, unsigned val) {
    asm volatile("s_waitcnt vmcnt(0) lgkmcnt(0)" ::: "memory");
    __syncthreads();
    if (threadIdx.x == 0)
        __hip_atomic_store(fown, val, __ATOMIC_RELAXED, ASCOPE);
}
__device__ __forceinline__ void bar_wait(unsigned* fbase, unsigned val) {
    if (threadIdx.x < 64) {
        for (;;) {
            unsigned v = __hip_atomic_load(fbase + threadIdx.x * FSTR,
                                           __ATOMIC_RELAXED, ASCOPE);
            if (__all(v >= val)) break;
            __builtin_amdgcn_s_sleep(1);
        }
    }
    asm volatile("" ::: "memory");
    __syncthreads();
}

// ---------------- one-time: WfT = [cW@wWx ; wWh]^T (768/col), bf = cb@wWx + wb,
// ---------------- rWT = [rWx ; rWh]^T (512/col), zero epoch flags
__global__ __launch_bounds__(256) void k_pre(
    const float* __restrict__ cW, const float* __restrict__ cb,
    const float* __restrict__ wWx, const float* __restrict__ wb,
    const float* __restrict__ rWx, const float* __restrict__ rWh,
    const float* __restrict__ wWh,
    float* __restrict__ WfT, float* __restrict__ rWT, float* __restrict__ bfv,
    unsigned* __restrict__ flg) {
    int bid = blockIdx.x, tid = threadIdx.x;
    if (bid < 512) {
        __shared__ float srow[512];
        srow[tid] = cW[(size_t)bid * 512 + tid];
        srow[256 + tid] = cW[(size_t)bid * 512 + 256 + tid];
        __syncthreads();
#pragma unroll
        for (int rep = 0; rep < 4; rep++) {
            int col = rep * 256 + tid;
            float a = 0.f;
#pragma unroll 4
            for (int c = 0; c < 512; c++) a += srow[c] * wWx[(size_t)c * 1024 + col];
            WfT[(size_t)col * 768 + bid] = a;
        }
    } else if (bid < 516) {
        int col = (bid - 512) * 256 + tid;
        float a = wb[col];
#pragma unroll 4
        for (int c = 0; c < 512; c++) a += cb[c] * wWx[(size_t)c * 1024 + col];
        bfv[col] = a;
    } else if (bid < 644) {
        int k0 = (bid - 516) * 2;
        for (int kk = k0; kk < k0 + 2; kk++)
            for (int col = tid; col < 1024; col += 256)
                rWT[(size_t)col * 512 + kk] = rWx[(size_t)kk * 1024 + col];
    } else if (bid < 772) {
        int k0 = (bid - 644) * 2;
        for (int kk = k0; kk < k0 + 2; kk++)
            for (int col = tid; col < 1024; col += 256)
                rWT[(size_t)col * 512 + 256 + kk] = rWh[(size_t)kk * 1024 + col];
    } else if (bid < 900) {
        int k0 = (bid - 772) * 2;
        for (int kk = k0; kk < k0 + 2; kk++)
            for (int col = tid; col < 1024; col += 256)
                WfT[(size_t)col * 768 + 512 + kk] = wWh[(size_t)kk * 1024 + col];
    } else {
        int idx = (bid - 900) * 256 + tid;
        flg[idx] = 0u;
    }
}

// ---------------- persistent kernel ----------------
__global__ __launch_bounds__(512, 1) void k_nse(
    const float* __restrict__ x, const float* __restrict__ rb,
    const float* __restrict__ rWT, const float* __restrict__ WfT,
    const float* __restrict__ bfv, float* __restrict__ st,
    float* __restrict__ out, unsigned* __restrict__ flg) {
    __shared__ float smem[32768 + 6144 + 64];
    float* memT = smem;           // [128][256] mem tile
    float* sh = smem + 32768;     // [8][768] staging; phase-A combine aliases head

    float* hrb[2] = { st, st + 8192 };
    float* hwb[2] = { st + 16384, st + 24576 };
    float* MSf    = st + 32768;   // [32][2]
    float* partMS = st + 32832;   // [256][2]
    float* partV  = st + 33344;   // [256][256]

    int g = blockIdx.x, tid = threadIdx.x;
    int w = tid >> 6, ln = tid & 63;
    int bA = g >> 3;                      // phase-A batch
    int bg = g >> 6, gl = g & 63;
    int j0 = gl * 4;
    unsigned* fA = flg + (bg * 64) * FSTR;
    unsigned* fB = flg + (256 + bg * 64) * FSTR;
    unsigned* fAo = fA + gl * FSTR;
    unsigned* fBo = fB + gl * FSTR;

    int jq = ln & 3, gate = (ln >> 2) & 3, ks = ln >> 4;
    int col = gate * KK + j0 + jq;
    int jl = ln & 3;
    int bw = bg * 8 + w;                  // this wave's b for reader / phase B
    float* shb = sh + w * 768;

    // Wf2 slice (m_rt rows 256..511 of col) register-resident forever
    const float4* wfc = (const float4*)(WfT + (size_t)col * 768);
    float4 w2[16];
#pragma unroll
    for (int i = 0; i < 16; i++) w2[i] = wfc[64 + i * 4 + ks];

    float crreg = 0.f, cwreg = 0.f, gpre = 0.f;

    // ---- prologue: mem tile <- x ; stage [x_0|0|0]; reader step 0 ----
    const float4* xsrc = (const float4*)(x + ((size_t)bA * LL + (size_t)(g & 7) * 128) * KK);
#pragma unroll
    for (int i = 0; i < 16; i++) ((float4*)memT)[tid + i * 512] = xsrc[tid + i * 512];
    {
        int q = ln;
        float* dst = shb;
        ((float4*)dst)[q] = ((const float4*)(x + (size_t)bw * LL * KK))[q];
        ((float4*)(dst + 256))[q] = make_float4(0.f, 0.f, 0.f, 0.f);
        __syncthreads();
        float acc = (ks == 0) ? rb[col] : 0.f;
        const float4* rwc = (const float4*)(rWT + (size_t)col * 512);
        const float4* ip = (const float4*)shb;
#pragma unroll 8
        for (int i = 0; i < 32; i++) {
            int idx = i * 4 + ks;
            float4 a = ip[idx], qv = rwc[idx];
            acc += a.x * qv.x + a.y * qv.y + a.z * qv.z + a.w * qv.w;
        }
        acc += __shfl_xor(acc, 16);
        acc += __shfl_xor(acc, 32);
        float gi = __shfl(acc, jl), gG = __shfl(acc, 8 + jl), go = __shfl(acc, 12 + jl);
        float cn = sigf(gi) * tanhf(gG);
        float hn = sigf(go) * tanhf(cn);
        crreg = cn;
        float pa = __shfl(hn, 2 * (ln & 31)), pb = __shfl(hn, 2 * (ln & 31) + 1);
        if (ln < 2) st_coh2(hrb[0] + bw * KK + j0 + 2 * ln, pa, pb);
    }
    bar_arrive(fBo, 1u);
    bar_wait(fB, 1u);

    float sprev[16];
    for (int t = 0; t < LL; t++) {
        int cur = t & 1, prv = cur ^ 1;
        // ===== phase A: batched dots + pipelined reduce + 2-pass softmax =====
        const float* hp = hrb[cur] + bA * KK + ln * 4;
        float2 ha = ld_coh2(hp), hc = ld_coh2(hp + 2);
        float4 h4 = make_float4(ha.x, ha.y, hc.x, hc.y);
        float dp[16];
        float* rowp = memT + w * 16 * KK;
        if (t > 0) {
            const float* wp0 = hwb[prv] + bA * KK + ln * 4;
            float2 wa = ld_coh2(wp0), wc = ld_coh2(wp0 + 2);
            float4 w4 = make_float4(wa.x, wa.y, wc.x, wc.y);
            float2 ms = ld_coh2(MSf + bA * 2);
            float Mprev = ms.x, invS = 1.0f / ms.y;
#pragma unroll
            for (int i = 0; i < 16; i++) {
                float4* vp = (float4*)(rowp + i * KK) + ln;
                float4 v = *vp;
                float z = __expf(sprev[i] - Mprev) * invS;
                float om = 1.0f - z;
                v.x = v.x * om + w4.x * z;
                v.y = v.y * om + w4.y * z;
                v.z = v.z * om + w4.z * z;
                v.w = v.w * om + w4.w * z;
                *vp = v;
                dp[i] = h4.x * v.x + h4.y * v.y + h4.z * v.z + h4.w * v.w;
            }
        } else {
#pragma unroll
            for (int i = 0; i < 16; i++) {
                float4 v = *((float4*)(rowp + i * KK) + ln);
                dp[i] = h4.x * v.x + h4.y * v.y + h4.z * v.z + h4.w * v.w;
            }
        }
        // stage-major butterfly: 16 independent chains, pipelined
#pragma unroll
        for (int m = 1; m < 64; m <<= 1) {
#pragma unroll
            for (int i = 0; i < 16; i++) dp[i] += __shfl_xor(dp[i], m);
        }
        float M16 = dp[0];
#pragma unroll
        for (int i = 1; i < 16; i++) M16 = fmaxf(M16, dp[i]);
        float Sw = 0.f;
        float4 Vw = make_float4(0.f, 0.f, 0.f, 0.f);
#pragma unroll
        for (int i = 0; i < 16; i++) {
            float e = __expf(dp[i] - M16);
            Sw += e;
            float4 v = *((float4*)(rowp + i * KK) + ln);
            Vw.x += e * v.x; Vw.y += e * v.y; Vw.z += e * v.z; Vw.w += e * v.w;
            sprev[i] = dp[i];
        }
        // block combine of 8 wave partials -> MALL
        float* sV = sh;
        float* sM8 = sh + 2048;
        float* sS8 = sM8 + 8;
        ((float4*)(sV + w * KK))[ln] = Vw;
        if (ln == 0) { sM8[w] = M16; sS8[w] = Sw; }
        __syncthreads();
        if (tid < 128) {
            float M = sM8[0];
#pragma unroll
            for (int q2 = 1; q2 < 8; q2++) M = fmaxf(M, sM8[q2]);
            float S = 0.f, V0 = 0.f, V1 = 0.f;
#pragma unroll
            for (int q2 = 0; q2 < 8; q2++) {
                float e = __expf(sM8[q2] - M);
                S += e * sS8[q2];
                V0 += e * sV[q2 * KK + 2 * tid];
                V1 += e * sV[q2 * KK + 2 * tid + 1];
            }
            st_coh2(partV + (size_t)g * KK + 2 * tid, V0, V1);
            if (tid == 0) st_coh2(partMS + g * 2, M, S);
        }
        bar_arrive(fAo, (unsigned)(t + 1));

        // ===== shadow: stage [x_{t+1}|hr_t|hw_{t-1}]; writer-PRE; reader t+1 =====
        {
            int q = ln;
            float* dst = shb;
            if (t + 1 < LL)
                ((float4*)dst)[q] =
                    ((const float4*)(x + ((size_t)bw * LL + (size_t)(t + 1)) * KK))[q];
            {
                const float* hq = hrb[cur] + bw * KK + q * 4;
                float2 a2 = ld_coh2(hq), c2 = ld_coh2(hq + 2);
                ((float4*)(dst + 256))[q] = make_float4(a2.x, a2.y, c2.x, c2.y);
            }
            if (t > 0) {
                const float* hq = hwb[prv] + bw * KK + q * 4;
                float2 a2 = ld_coh2(hq), c2 = ld_coh2(hq + 2);
                ((float4*)(dst + 512))[q] = make_float4(a2.x, a2.y, c2.x, c2.y);
            } else {
                ((float4*)(dst + 512))[q] = make_float4(0.f, 0.f, 0.f, 0.f);
            }
            __syncthreads();
            // writer-pre: rows 0..255 (hr) + rows 512..767 (hw)
            float acc = (ks == 0) ? bfv[col] : 0.f;
            const float4* ip1 = (const float4*)(shb + 256);
            const float4* ip2 = (const float4*)(shb + 512);
#pragma unroll 8
            for (int i = 0; i < 16; i++) {
                int idx = i * 4 + ks;
                float4 a = ip1[idx], qv = wfc[idx];
                acc += a.x * qv.x + a.y * qv.y + a.z * qv.z + a.w * qv.w;
            }
#pragma unroll 8
            for (int i = 0; i < 16; i++) {
                int idx = i * 4 + ks;
                float4 a = ip2[idx], qv = wfc[128 + idx];
                acc += a.x * qv.x + a.y * qv.y + a.z * qv.z + a.w * qv.w;
            }
            gpre = acc;
            // reader t+1 over [x|hr]
            if (t + 1 < LL) {
                float racc = (ks == 0) ? rb[col] : 0.f;
                const float4* rwc = (const float4*)(rWT + (size_t)col * 512);
                const float4* ip = (const float4*)shb;
#pragma unroll 8
                for (int i = 0; i < 32; i++) {
                    int idx = i * 4 + ks;
                    float4 a = ip[idx], qv = rwc[idx];
                    racc += a.x * qv.x + a.y * qv.y + a.z * qv.z + a.w * qv.w;
                }
                racc += __shfl_xor(racc, 16);
                racc += __shfl_xor(racc, 32);
                float gi = __shfl(racc, jl), gf = __shfl(racc, 4 + jl);
                float gG = __shfl(racc, 8 + jl), go = __shfl(racc, 12 + jl);
                float cn = sigf(gf) * crreg + sigf(gi) * tanhf(gG);
                float hn = sigf(go) * tanhf(cn);
                crreg = cn;
                float pa = __shfl(hn, 2 * (ln & 31)), pb = __shfl(hn, 2 * (ln & 31) + 1);
                if (ln < 2) st_coh2(hrb[prv] + bw * KK + j0 + 2 * ln, pa, pb);
            }
        }

        // ===== per-WAVE waitA: only this wave's 8 producer flags =====
        {
            unsigned tgt = (unsigned)(t + 1);
            for (;;) {
                unsigned v = tgt;
                if (ln < 8)
                    v = __hip_atomic_load(fA + (8 * w + ln) * FSTR, __ATOMIC_RELAXED, ASCOPE);
                if (__all(v >= tgt)) break;
                __builtin_amdgcn_s_sleep(1);
            }
        }
        // ===== B-post (per wave, b = bw): m_rt combine + register matvec =====
        {
            float M = -INFINITY;
            float2 pms[8];
#pragma unroll
            for (int q2 = 0; q2 < 8; q2++) {
                pms[q2] = ld_coh2(partMS + (bw * 8 + q2) * 2);
                M = fmaxf(M, pms[q2].x);
            }
            float S = 0.f;
            float4 V = make_float4(0.f, 0.f, 0.f, 0.f);
#pragma unroll
            for (int q2 = 0; q2 < 8; q2++) {
                float e = __expf(pms[q2].x - M);
                S += e * pms[q2].y;
                const float* pv = partV + (size_t)(bw * 8 + q2) * KK + ln * 4;
                float2 v01 = ld_coh2(pv), v23 = ld_coh2(pv + 2);
                V.x += e * v01.x; V.y += e * v01.y; V.z += e * v23.x; V.w += e * v23.y;
            }
            float rS = 1.0f / S;
            ((float4*)shb)[ln] = make_float4(V.x * rS, V.y * rS, V.z * rS, V.w * rS);
            if (gl == 0 && ln == 0) st_coh2(MSf + bw * 2, M, S);
            float acc = gpre;
            const float4* ip = (const float4*)shb;
#pragma unroll
            for (int i = 0; i < 16; i++) {
                int idx = i * 4 + ks;
                float4 a = ip[idx];
                acc += a.x * w2[i].x + a.y * w2[i].y + a.z * w2[i].z + a.w * w2[i].w;
            }
            acc += __shfl_xor(acc, 16);
            acc += __shfl_xor(acc, 32);
            float gi = __shfl(acc, jl), gf = __shfl(acc, 4 + jl);
            float gG = __shfl(acc, 8 + jl), go = __shfl(acc, 12 + jl);
            float cp = (t > 0) ? cwreg : 0.f;
            float cn = sigf(gf) * cp + sigf(gi) * tanhf(gG);
            float hn = sigf(go) * tanhf(cn);
            cwreg = cn;
            float pa = __shfl(hn, 2 * (ln & 31)), pb = __shfl(hn, 2 * (ln & 31) + 1);
            if (ln < 2) {
                st_coh2(hwb[cur] + bw * KK + j0 + 2 * ln, pa, pb);
                *(float2*)(out + ((size_t)bw * LL + t) * KK + j0 + 2 * ln) =
                    make_float2(pa, pb);
            }
        }
        bar_arrive(fBo, (unsigned)(t + 2));
        bar_wait(fB, (unsigned)(t + 2));
    }
}

// ---------------- host ----------------
extern "C" void kernel_launch(void* const* d_in, const int* in_sizes, int n_in,
                              void* d_out, int out_size, void* d_ws, size_t ws_size,
                              hipStream_t stream) {
    const float* x   = (const float*)d_in[0];
    const float* rWx = (const float*)d_in[1];
    const float* rWh = (const float*)d_in[2];
    const float* rb  = (const float*)d_in[3];
    const float* wWx = (const float*)d_in[4];
    const float* wWh = (const float*)d_in[5];
    const float* wb  = (const float*)d_in[6];
    const float* cW  = (const float*)d_in[7];
    const float* cb  = (const float*)d_in[8];
    float* out = (float*)d_out;

    float* ws = (float*)d_ws;
    float* WfT = ws;                        // 1024*768
    float* rWT = ws + 786432;               // 1024*512
    float* bfv = ws + 786432 + 524288;      // 1024
    float* st  = bfv + 1024;                // states + partials (98880 floats)
    unsigned* flg = (unsigned*)(st + 98880); // 512 flags x 16-dword stride = 8192 u32

    k_pre<<<932, 256, 0, stream>>>(cW, cb, wWx, wb, rWx, rWh, wWh, WfT, rWT, bfv, flg);

    const float* a_x = x; const float* a_rb = rb;
    const float* a_rWT = rWT; const float* a_WfT = WfT; const float* a_bf = bfv;
    float* a_st = st; float* a_out = out; unsigned* a_flg = flg;
    void* args[] = { &a_x, &a_rb, &a_rWT, &a_WfT, &a_bf, &a_st, &a_out, &a_flg };
    hipLaunchCooperativeKernel(reinterpret_cast<void*>(k_nse), dim3(256), dim3(512),
                               args, 0, stream);
}

// Round 7
// 15008.861 us; speedup vs baseline: 5.8798x; 1.7717x over previous
//
#include <hip/hip_runtime.h>
#include <math.h>

// NSE B=32 L=1024 K=256 — persistent kernel R7.
// vs R5: coalesced weight lanes (ks in low bits), LDS transpose-reduce for scores,
// M/S from local LDS, x/hr/hw prefetch at A-top, gather issued before matvecs,
// reader weights half register-resident, per-wave staging (no extra syncthreads).

#define Bb 32
#define LL 1024
#define KK 256
#define ASCOPE __HIP_MEMORY_SCOPE_AGENT
#define FSTR 16

__device__ __forceinline__ float sigf(float v) { return 1.0f / (1.0f + __expf(-v)); }

__device__ __forceinline__ void st_coh2(float* p, float a, float b) {
    float2 v = make_float2(a, b);
    __hip_atomic_store((unsigned long long*)p,
                       __builtin_bit_cast(unsigned long long, v),
                       __ATOMIC_RELAXED, ASCOPE);
}
__device__ __forceinline__ float2 ld_coh2(const float* p) {
    unsigned long long u = __hip_atomic_load((const unsigned long long*)p,
                                             __ATOMIC_RELAXED, ASCOPE);
    return __builtin_bit_cast(float2, u);
}

__device__ __forceinline__ void bar_arrive(unsigned* fown, unsigned val) {
    asm volatile("s_waitcnt vmcnt(0) lgkmcnt(0)" ::: "memory");
    __syncthreads();
    if (threadIdx.x == 0)
        __hip_atomic_store(fown, val, __ATOMIC_RELAXED, ASCOPE);
}
__device__ __forceinline__ void bar_wait(unsigned* fbase, unsigned val) {
    if (threadIdx.x < 64) {
        for (;;) {
            unsigned v = __hip_atomic_load(fbase + threadIdx.x * FSTR,
                                           __ATOMIC_RELAXED, ASCOPE);
            if (__all(v >= val)) break;
            __builtin_amdgcn_s_sleep(1);
        }
    }
    asm volatile("" ::: "memory");
    __syncthreads();
}

// ---------------- one-time: WfT = [cW@wWx ; wWh]^T (768/col), bf = cb@wWx + wb,
// ---------------- rWT = [rWx ; rWh]^T (512/col), zero epoch flags
__global__ __launch_bounds__(256) void k_pre(
    const float* __restrict__ cW, const float* __restrict__ cb,
    const float* __restrict__ wWx, const float* __restrict__ wb,
    const float* __restrict__ rWx, const float* __restrict__ rWh,
    const float* __restrict__ wWh,
    float* __restrict__ WfT, float* __restrict__ rWT, float* __restrict__ bfv,
    unsigned* __restrict__ flg) {
    int bid = blockIdx.x, tid = threadIdx.x;
    if (bid < 512) {
        __shared__ float srow[512];
        srow[tid] = cW[(size_t)bid * 512 + tid];
        srow[256 + tid] = cW[(size_t)bid * 512 + 256 + tid];
        __syncthreads();
#pragma unroll
        for (int rep = 0; rep < 4; rep++) {
            int col = rep * 256 + tid;
            float a = 0.f;
#pragma unroll 4
            for (int c = 0; c < 512; c++) a += srow[c] * wWx[(size_t)c * 1024 + col];
            WfT[(size_t)col * 768 + bid] = a;
        }
    } else if (bid < 516) {
        int col = (bid - 512) * 256 + tid;
        float a = wb[col];
#pragma unroll 4
        for (int c = 0; c < 512; c++) a += cb[c] * wWx[(size_t)c * 1024 + col];
        bfv[col] = a;
    } else if (bid < 644) {
        int k0 = (bid - 516) * 2;
        for (int kk = k0; kk < k0 + 2; kk++)
            for (int col = tid; col < 1024; col += 256)
                rWT[(size_t)col * 512 + kk] = rWx[(size_t)kk * 1024 + col];
    } else if (bid < 772) {
        int k0 = (bid - 644) * 2;
        for (int kk = k0; kk < k0 + 2; kk++)
            for (int col = tid; col < 1024; col += 256)
                rWT[(size_t)col * 512 + 256 + kk] = rWh[(size_t)kk * 1024 + col];
    } else if (bid < 900) {
        int k0 = (bid - 772) * 2;
        for (int kk = k0; kk < k0 + 2; kk++)
            for (int col = tid; col < 1024; col += 256)
                WfT[(size_t)col * 768 + 512 + kk] = wWh[(size_t)kk * 1024 + col];
    } else {
        int idx = (bid - 900) * 256 + tid;
        flg[idx] = 0u;
    }
}

// ---------------- persistent kernel ----------------
__global__ __launch_bounds__(512, 1) void k_nse(
    const float* __restrict__ x, const float* __restrict__ rb,
    const float* __restrict__ rWT, const float* __restrict__ WfT,
    const float* __restrict__ bfv, float* __restrict__ st,
    float* __restrict__ out, unsigned* __restrict__ flg) {
    __shared__ float smem[32768 + 6144 + 160];
    float* memT   = smem;                    // [128][256]
    float* arena  = smem + 32768;            // 6144 fl: A-phase [8][640] / staging [8][768]
    float* sMw    = smem + 32768 + 6144;     // 8
    float* sSw    = sMw + 8;                 // 8
    float* sMS    = sSw + 8;                 // [8][2]
    float* sScore = sMS + 16;                // [8][16]

    float* hrb[2] = { st, st + 8192 };
    float* hwb[2] = { st + 16384, st + 24576 };
    float* partMS = st + 32832;              // [256][2]
    float* partV  = st + 33344;              // [256][256]

    int g = blockIdx.x, tid = threadIdx.x;
    int w = tid >> 6, ln = tid & 63;
    int bA = g >> 3;
    int bg = g >> 6, gl = g & 63;
    int j0 = gl * 4;
    int wstar = gl >> 3;                     // wave whose bw == bA
    unsigned* fA = flg + (bg * 64) * FSTR;
    unsigned* fB = flg + (256 + bg * 64) * FSTR;
    unsigned* fAo = fA + gl * FSTR;
    unsigned* fBo = fB + gl * FSTR;

    // coalesced lane map: ks in LOW bits
    int ks = ln & 3, jq = (ln >> 2) & 3, gate = ln >> 4;
    int col = gate * KK + j0 + jq;
    int jl = ln & 3;
    int bw = bg * 8 + w;
    float* shb = arena + w * 768;            // staging [x|hr|hw], m_rt over x
    float* sT  = arena + w * 640;            // transpose [64][10] (aliases Vw area)

    const float4* wfc = (const float4*)(WfT + (size_t)col * 768);
    const float4* rwc = (const float4*)(rWT + (size_t)col * 512);
    float4 w2[16];
#pragma unroll
    for (int i = 0; i < 16; i++) w2[i] = wfc[64 + i * 4 + ks];
    float4 rw1[8];
#pragma unroll
    for (int i = 0; i < 8; i++) rw1[i] = rwc[i * 4 + ks];

    float crreg = 0.f, cwreg = 0.f;

    // ---- prologue: memT <- x ; stage [x0|0]; reader step 0 ----
    const float4* xsrc = (const float4*)(x + ((size_t)bA * LL + (size_t)(g & 7) * 128) * KK);
#pragma unroll
    for (int i = 0; i < 16; i++) ((float4*)memT)[tid + i * 512] = xsrc[tid + i * 512];
    {
        ((float4*)shb)[ln] = ((const float4*)(x + (size_t)bw * LL * KK))[ln];
        ((float4*)(shb + 256))[ln] = make_float4(0.f, 0.f, 0.f, 0.f);
        float racc = (ks == 0) ? rb[col] : 0.f;
        const float4* ip = (const float4*)shb;
#pragma unroll
        for (int i = 0; i < 8; i++) {
            float4 a = ip[i * 4 + ks];
            racc += a.x * rw1[i].x + a.y * rw1[i].y + a.z * rw1[i].z + a.w * rw1[i].w;
        }
#pragma unroll 8
        for (int i = 8; i < 32; i++) {
            int idx = i * 4 + ks;
            float4 a = ip[idx], q = rwc[idx];
            racc += a.x * q.x + a.y * q.y + a.z * q.z + a.w * q.w;
        }
        racc += __shfl_xor(racc, 1);
        racc += __shfl_xor(racc, 2);
        float gi = __shfl(racc, 4 * jl), gG = __shfl(racc, 32 + 4 * jl);
        float go = __shfl(racc, 48 + 4 * jl);
        float cn = sigf(gi) * tanhf(gG);
        float hn = sigf(go) * tanhf(cn);
        crreg = cn;
        float pa = __shfl(hn, 2 * (ln & 31)), pb = __shfl(hn, 2 * (ln & 31) + 1);
        if (ln < 2) st_coh2(hrb[0] + bw * KK + j0 + 2 * ln, pa, pb);
    }
    bar_arrive(fBo, 1u);
    float4 xreg = ((const float4*)(x + ((size_t)bw * LL + 1) * KK))[ln];  // prefetch x_1
    bar_wait(fB, 1u);

    for (int t = 0; t < LL; t++) {
        int cur = t & 1, prv = cur ^ 1;
        // ===== A-top: issue all MALL loads together =====
        const float* hp = hrb[cur] + bA * KK + ln * 4;
        float2 ha = ld_coh2(hp), hc = ld_coh2(hp + 2);
        float4 h4 = make_float4(ha.x, ha.y, hc.x, hc.y);
        float4 hrs2, hws2, w4 = make_float4(0.f, 0.f, 0.f, 0.f);
        {
            const float* hq = hrb[cur] + bw * KK + ln * 4;
            float2 a = ld_coh2(hq), c = ld_coh2(hq + 2);
            hrs2 = make_float4(a.x, a.y, c.x, c.y);
        }
        float Mprev = 0.f, invS = 0.f;
        if (t > 0) {
            const float* wp0 = hwb[prv] + bA * KK + ln * 4;
            float2 wa = ld_coh2(wp0), wc = ld_coh2(wp0 + 2);
            w4 = make_float4(wa.x, wa.y, wc.x, wc.y);
            const float* hq = hwb[prv] + bw * KK + ln * 4;
            float2 a = ld_coh2(hq), c = ld_coh2(hq + 2);
            hws2 = make_float4(a.x, a.y, c.x, c.y);
            Mprev = sMS[wstar * 2];
            invS = 1.0f / sMS[wstar * 2 + 1];
        } else {
            hws2 = make_float4(0.f, 0.f, 0.f, 0.f);
        }
        // ===== phase A: update + dots =====
        float dp[16];
        float* rowp = memT + w * 16 * KK;
        if (t > 0) {
            float scs[16];
            {
                const float4* sp = (const float4*)(sScore + w * 16);
#pragma unroll
                for (int q2 = 0; q2 < 4; q2++) {
                    float4 s4 = sp[q2];
                    scs[q2 * 4 + 0] = s4.x; scs[q2 * 4 + 1] = s4.y;
                    scs[q2 * 4 + 2] = s4.z; scs[q2 * 4 + 3] = s4.w;
                }
            }
#pragma unroll
            for (int i = 0; i < 16; i++) {
                float4* vp = (float4*)(rowp + i * KK) + ln;
                float4 v = *vp;
                float z = __expf(scs[i] - Mprev) * invS;
                float om = 1.0f - z;
                v.x = v.x * om + w4.x * z;
                v.y = v.y * om + w4.y * z;
                v.z = v.z * om + w4.z * z;
                v.w = v.w * om + w4.w * z;
                *vp = v;
                dp[i] = h4.x * v.x + h4.y * v.y + h4.z * v.z + h4.w * v.w;
            }
        } else {
#pragma unroll
            for (int i = 0; i < 16; i++) {
                float4 v = *((float4*)(rowp + i * KK) + ln);
                dp[i] = h4.x * v.x + h4.y * v.y + h4.z * v.z + h4.w * v.w;
            }
        }
        // ===== transpose-reduce (two 8-row halves), scores -> sScore =====
        {
            int rr = ln >> 3, kk2 = ln & 7;
#pragma unroll
            for (int hh = 0; hh < 2; hh++) {
                int o = hh * 8;
                *(float2*)(sT + ln * 10 + 0) = make_float2(dp[o + 0], dp[o + 1]);
                *(float2*)(sT + ln * 10 + 2) = make_float2(dp[o + 2], dp[o + 3]);
                *(float2*)(sT + ln * 10 + 4) = make_float2(dp[o + 4], dp[o + 5]);
                *(float2*)(sT + ln * 10 + 6) = make_float2(dp[o + 6], dp[o + 7]);
                float ps = 0.f;
#pragma unroll
                for (int j = 0; j < 8; j++) ps += sT[(j * 8 + kk2) * 10 + rr];
                ps += __shfl_xor(ps, 1);
                ps += __shfl_xor(ps, 2);
                ps += __shfl_xor(ps, 4);
                if (kk2 == 0) sScore[w * 16 + o + rr] = ps;
            }
        }
        // ===== softmax partials (scores wave-uniform from LDS) =====
        {
            float scs2[16];
            const float4* sp = (const float4*)(sScore + w * 16);
#pragma unroll
            for (int q2 = 0; q2 < 4; q2++) {
                float4 s4 = sp[q2];
                scs2[q2 * 4 + 0] = s4.x; scs2[q2 * 4 + 1] = s4.y;
                scs2[q2 * 4 + 2] = s4.z; scs2[q2 * 4 + 3] = s4.w;
            }
            float M16 = scs2[0];
#pragma unroll
            for (int i = 1; i < 16; i++) M16 = fmaxf(M16, scs2[i]);
            float Sw = 0.f;
            float4 Vw = make_float4(0.f, 0.f, 0.f, 0.f);
#pragma unroll
            for (int i = 0; i < 16; i++) {
                float e = __expf(scs2[i] - M16);
                Sw += e;
                float4 v = *((float4*)(rowp + i * KK) + ln);
                Vw.x += e * v.x; Vw.y += e * v.y; Vw.z += e * v.z; Vw.w += e * v.w;
            }
            ((float4*)(arena + w * 640))[ln] = Vw;   // alias sT (wave-local, reads done)
            if (ln == 0) { sMw[w] = M16; sSw[w] = Sw; }
        }
        __syncthreads();
        if (tid < 128) {
            float M = sMw[0];
#pragma unroll
            for (int q2 = 1; q2 < 8; q2++) M = fmaxf(M, sMw[q2]);
            float S = 0.f, V0 = 0.f, V1 = 0.f;
#pragma unroll
            for (int q2 = 0; q2 < 8; q2++) {
                float e = __expf(sMw[q2] - M);
                S += e * sSw[q2];
                V0 += e * arena[q2 * 640 + 2 * tid];
                V1 += e * arena[q2 * 640 + 2 * tid + 1];
            }
            st_coh2(partV + (size_t)g * KK + 2 * tid, V0, V1);
            if (tid == 0) st_coh2(partMS + g * 2, M, S);
        }
        bar_arrive(fAo, (unsigned)(t + 1));

        // ===== stage (per-wave, registers -> LDS, no barrier needed) =====
        if (t + 1 < LL) ((float4*)shb)[ln] = xreg;
        ((float4*)(shb + 256))[ln] = hrs2;
        ((float4*)(shb + 512))[ln] = hws2;

        // ===== per-wave waitA on 8 producer flags =====
        {
            unsigned tgt = (unsigned)(t + 1);
            for (;;) {
                unsigned v = tgt;
                if (ln < 8)
                    v = __hip_atomic_load(fA + (8 * w + ln) * FSTR, __ATOMIC_RELAXED, ASCOPE);
                if (__all(v >= tgt)) break;
                __builtin_amdgcn_s_sleep(1);
            }
        }
        // ===== issue B-gather first (MALL latency hides under matvec streams) =====
        float2 pms[8], pva[8], pvb[8];
#pragma unroll
        for (int q2 = 0; q2 < 8; q2++) {
            pms[q2] = ld_coh2(partMS + (bw * 8 + q2) * 2);
            const float* pv = partV + (size_t)(bw * 8 + q2) * KK + ln * 4;
            pva[q2] = ld_coh2(pv);
            pvb[q2] = ld_coh2(pv + 2);
        }
        // ===== writer-pre: rows 0..255 (hr) + 512..767 (hw), coalesced stream =====
        float gpre;
        {
            float acc = (ks == 0) ? bfv[col] : 0.f;
            const float4* ip1 = (const float4*)(shb + 256);
            const float4* ip2 = (const float4*)(shb + 512);
#pragma unroll 8
            for (int i = 0; i < 16; i++) {
                int idx = i * 4 + ks;
                float4 a = ip1[idx], q = wfc[idx];
                acc += a.x * q.x + a.y * q.y + a.z * q.z + a.w * q.w;
            }
#pragma unroll 8
            for (int i = 0; i < 16; i++) {
                int idx = i * 4 + ks;
                float4 a = ip2[idx], q = wfc[128 + idx];
                acc += a.x * q.x + a.y * q.y + a.z * q.z + a.w * q.w;
            }
            gpre = acc;
        }
        // ===== reader t+1 over [x|hr] =====
        if (t + 1 < LL) {
            float racc = (ks == 0) ? rb[col] : 0.f;
            const float4* ip = (const float4*)shb;
#pragma unroll
            for (int i = 0; i < 8; i++) {
                float4 a = ip[i * 4 + ks];
                racc += a.x * rw1[i].x + a.y * rw1[i].y + a.z * rw1[i].z + a.w * rw1[i].w;
            }
#pragma unroll 8
            for (int i = 8; i < 32; i++) {
                int idx = i * 4 + ks;
                float4 a = ip[idx], q = rwc[idx];
                racc += a.x * q.x + a.y * q.y + a.z * q.z + a.w * q.w;
            }
            racc += __shfl_xor(racc, 1);
            racc += __shfl_xor(racc, 2);
            float gi = __shfl(racc, 4 * jl), gf = __shfl(racc, 16 + 4 * jl);
            float gG = __shfl(racc, 32 + 4 * jl), go = __shfl(racc, 48 + 4 * jl);
            float cn = sigf(gf) * crreg + sigf(gi) * tanhf(gG);
            float hn = sigf(go) * tanhf(cn);
            crreg = cn;
            float pa = __shfl(hn, 2 * (ln & 31)), pb = __shfl(hn, 2 * (ln & 31) + 1);
            if (ln < 2) st_coh2(hrb[prv] + bw * KK + j0 + 2 * ln, pa, pb);
        }
        // ===== B-post: combine + register matvec + LSTM pointwise =====
        {
            float M = pms[0].x;
#pragma unroll
            for (int q2 = 1; q2 < 8; q2++) M = fmaxf(M, pms[q2].x);
            float S = 0.f;
            float4 V = make_float4(0.f, 0.f, 0.f, 0.f);
#pragma unroll
            for (int q2 = 0; q2 < 8; q2++) {
                float e = __expf(pms[q2].x - M);
                S += e * pms[q2].y;
                V.x += e * pva[q2].x; V.y += e * pva[q2].y;
                V.z += e * pvb[q2].x; V.w += e * pvb[q2].y;
            }
            float rS = 1.0f / S;
            ((float4*)shb)[ln] = make_float4(V.x * rS, V.y * rS, V.z * rS, V.w * rS);
            if (ln == 0) { sMS[w * 2] = M; sMS[w * 2 + 1] = S; }
            float acc = gpre;
            const float4* ip = (const float4*)shb;
#pragma unroll
            for (int i = 0; i < 16; i++) {
                float4 a = ip[i * 4 + ks];
                acc += a.x * w2[i].x + a.y * w2[i].y + a.z * w2[i].z + a.w * w2[i].w;
            }
            acc += __shfl_xor(acc, 1);
            acc += __shfl_xor(acc, 2);
            float gi = __shfl(acc, 4 * jl), gf = __shfl(acc, 16 + 4 * jl);
            float gG = __shfl(acc, 32 + 4 * jl), go = __shfl(acc, 48 + 4 * jl);
            float cp = (t > 0) ? cwreg : 0.f;
            float cn = sigf(gf) * cp + sigf(gi) * tanhf(gG);
            float hn = sigf(go) * tanhf(cn);
            cwreg = cn;
            float pa = __shfl(hn, 2 * (ln & 31)), pb = __shfl(hn, 2 * (ln & 31) + 1);
            if (ln < 2) {
                st_coh2(hwb[cur] + bw * KK + j0 + 2 * ln, pa, pb);
                *(float2*)(out + ((size_t)bw * LL + t) * KK + j0 + 2 * ln) =
                    make_float2(pa, pb);
            }
        }
        bar_arrive(fBo, (unsigned)(t + 2));
        if (t + 2 < LL)
            xreg = ((const float4*)(x + ((size_t)bw * LL + (size_t)(t + 2)) * KK))[ln];
        bar_wait(fB, (unsigned)(t + 2));
    }
}

// ---------------- host ----------------
extern "C" void kernel_launch(void* const* d_in, const int* in_sizes, int n_in,
                              void* d_out, int out_size, void* d_ws, size_t ws_size,
                              hipStream_t stream) {
    const float* x   = (const float*)d_in[0];
    const float* rWx = (const float*)d_in[1];
    const float* rWh = (const float*)d_in[2];
    const float* rb  = (const float*)d_in[3];
    const float* wWx = (const float*)d_in[4];
    const float* wWh = (const float*)d_in[5];
    const float* wb  = (const float*)d_in[6];
    const float* cW  = (const float*)d_in[7];
    const float* cb  = (const float*)d_in[8];
    float* out = (float*)d_out;

    float* ws = (float*)d_ws;
    float* WfT = ws;                        // 1024*768
    float* rWT = ws + 786432;               // 1024*512
    float* bfv = ws + 786432 + 524288;      // 1024
    float* st  = bfv + 1024;                // states + partials (98880 floats)
    unsigned* flg = (unsigned*)(st + 98880); // 512 flags x 16-dword stride

    k_pre<<<932, 256, 0, stream>>>(cW, cb, wWx, wb, rWx, rWh, wWh, WfT, rWT, bfv, flg);

    const float* a_x = x; const float* a_rb = rb;
    const float* a_rWT = rWT; const float* a_WfT = WfT; const float* a_bf = bfv;
    float* a_st = st; float* a_out = out; unsigned* a_flg = flg;
    void* args[] = { &a_x, &a_rb, &a_rWT, &a_WfT, &a_bf, &a_st, &a_out, &a_flg };
    hipLaunchCooperativeKernel(reinterpret_cast<void*>(k_nse), dim3(256), dim3(512),
                               args, 0, stream);
}

// Round 8
// 13154.843 us; speedup vs baseline: 6.7085x; 1.1409x over previous
//
#include <hip/hip_runtime.h>
#include <math.h>

// NSE B=32 L=1024 K=256 — persistent kernel R8.
// vs R7: deduped weight streams (lane map b|ks|cp: weight addr shared by 8 b-lanes,
// block reads each weight once, not 8x), inputs/m_rt in LDS arena [8][776],
// ks-rotation kills LDS bank aliasing, transpose stride 9 (conflict-free),
// matvec streams moved BEFORE waitA, pointwise+cell-state on wave0 tid<32.

#define Bb 32
#define LL 1024
#define KK 256
#define AR 776     // arena stride (floats): 768 + 8 pad (bank spread for b)
#define ASCOPE __HIP_MEMORY_SCOPE_AGENT
#define FSTR 16

__device__ __forceinline__ float sigf(float v) { return 1.0f / (1.0f + __expf(-v)); }

__device__ __forceinline__ void st_coh2(float* p, float a, float b) {
    float2 v = make_float2(a, b);
    __hip_atomic_store((unsigned long long*)p,
                       __builtin_bit_cast(unsigned long long, v),
                       __ATOMIC_RELAXED, ASCOPE);
}
__device__ __forceinline__ float2 ld_coh2(const float* p) {
    unsigned long long u = __hip_atomic_load((const unsigned long long*)p,
                                             __ATOMIC_RELAXED, ASCOPE);
    return __builtin_bit_cast(float2, u);
}

__device__ __forceinline__ void bar_arrive(unsigned* fown, unsigned val) {
    asm volatile("s_waitcnt vmcnt(0) lgkmcnt(0)" ::: "memory");
    __syncthreads();
    if (threadIdx.x == 0)
        __hip_atomic_store(fown, val, __ATOMIC_RELAXED, ASCOPE);
}
__device__ __forceinline__ void bar_wait(unsigned* fbase, unsigned val) {
    if (threadIdx.x < 64) {
        for (;;) {
            unsigned v = __hip_atomic_load(fbase + threadIdx.x * FSTR,
                                           __ATOMIC_RELAXED, ASCOPE);
            if (__all(v >= val)) break;
            __builtin_amdgcn_s_sleep(1);
        }
    }
    asm volatile("" ::: "memory");
    __syncthreads();
}

// ---------------- one-time precompute (unchanged) ----------------
__global__ __launch_bounds__(256) void k_pre(
    const float* __restrict__ cW, const float* __restrict__ cb,
    const float* __restrict__ wWx, const float* __restrict__ wb,
    const float* __restrict__ rWx, const float* __restrict__ rWh,
    const float* __restrict__ wWh,
    float* __restrict__ WfT, float* __restrict__ rWT, float* __restrict__ bfv,
    unsigned* __restrict__ flg) {
    int bid = blockIdx.x, tid = threadIdx.x;
    if (bid < 512) {
        __shared__ float srow[512];
        srow[tid] = cW[(size_t)bid * 512 + tid];
        srow[256 + tid] = cW[(size_t)bid * 512 + 256 + tid];
        __syncthreads();
#pragma unroll
        for (int rep = 0; rep < 4; rep++) {
            int col = rep * 256 + tid;
            float a = 0.f;
#pragma unroll 4
            for (int c = 0; c < 512; c++) a += srow[c] * wWx[(size_t)c * 1024 + col];
            WfT[(size_t)col * 768 + bid] = a;
        }
    } else if (bid < 516) {
        int col = (bid - 512) * 256 + tid;
        float a = wb[col];
#pragma unroll 4
        for (int c = 0; c < 512; c++) a += cb[c] * wWx[(size_t)c * 1024 + col];
        bfv[col] = a;
    } else if (bid < 644) {
        int k0 = (bid - 516) * 2;
        for (int kk = k0; kk < k0 + 2; kk++)
            for (int col = tid; col < 1024; col += 256)
                rWT[(size_t)col * 512 + kk] = rWx[(size_t)kk * 1024 + col];
    } else if (bid < 772) {
        int k0 = (bid - 644) * 2;
        for (int kk = k0; kk < k0 + 2; kk++)
            for (int col = tid; col < 1024; col += 256)
                rWT[(size_t)col * 512 + 256 + kk] = rWh[(size_t)kk * 1024 + col];
    } else if (bid < 900) {
        int k0 = (bid - 772) * 2;
        for (int kk = k0; kk < k0 + 2; kk++)
            for (int col = tid; col < 1024; col += 256)
                WfT[(size_t)col * 768 + 512 + kk] = wWh[(size_t)kk * 1024 + col];
    } else {
        int idx = (bid - 900) * 256 + tid;
        flg[idx] = 0u;
    }
}

// ---------------- persistent kernel ----------------
__global__ __launch_bounds__(512, 1) void k_nse(
    const float* __restrict__ x, const float* __restrict__ rb,
    const float* __restrict__ rWT, const float* __restrict__ WfT,
    const float* __restrict__ bfv, float* __restrict__ st,
    float* __restrict__ out, unsigned* __restrict__ flg) {
    __shared__ float smem[32768 + 8 * AR + 8 + 8 + 16 + 128 + 128 + 128];
    float* memT   = smem;                 // [128][256]
    float* arena  = smem + 32768;         // [8][AR]: x/m_rt[0,256) hr[256,512) hw[512,768)
    float* sMw    = arena + 8 * AR;       // 8
    float* sSw    = sMw + 8;              // 8
    float* sMS    = sSw + 8;              // [8][2] per-b (M,S)
    float* sScore = sMS + 16;             // [8][16]
    float* sGr    = sScore + 128;         // [16][8] reader gates
    float* sGw    = sGr + 128;            // [16][8] writer gates

    float* hrb[2] = { st, st + 8192 };
    float* hwb[2] = { st + 16384, st + 24576 };
    float* partMS = st + 32832;           // [256][2]
    float* partV  = st + 33344;           // [256][256]

    int g = blockIdx.x, tid = threadIdx.x;
    int w = tid >> 6, ln = tid & 63;
    int bA = g >> 3;                      // phase-A batch
    int bg = g >> 6, gl = g & 63;
    int j0 = gl * 4;
    unsigned* fA = flg + (bg * 64) * FSTR;
    unsigned* fB = flg + (256 + bg * 64) * FSTR;
    unsigned* fAo = fA + gl * FSTR;
    unsigned* fBo = fB + gl * FSTR;

    // matvec lane map: b in low 3 bits, ks 2 bits, cp 1 bit
    int bln = ln & 7, ks = (ln >> 3) & 3, cp = ln >> 5;
    int c = 2 * w + cp;                   // 0..15 block-local col
    int gate = c >> 2, jlc = c & 3;
    int col = gate * KK + j0 + jlc;
    int bglw = bg * 8 + w;                // this wave's staging/combine batch

    const float4* wfc = (const float4*)(WfT + (size_t)col * 768);
    const float4* rwc = (const float4*)(rWT + (size_t)col * 512);
    float4 w2[16];                        // m_rt rows (256..511) of col, ks slice, rotated
#pragma unroll
    for (int i = 0; i < 16; i++) w2[i] = wfc[64 + ks * 16 + ((i + 3 * ks) & 15)];

    float crreg = 0.f, cwreg = 0.f;       // cell states for (pb,pj) on wave0 tid<32

    // ---- prologue: memT <- x ; stage [x_0 | 0]; reader step 0 ----
    const float4* xsrc = (const float4*)(x + ((size_t)bA * LL + (size_t)(g & 7) * 128) * KK);
#pragma unroll
    for (int i = 0; i < 16; i++) ((float4*)memT)[tid + i * 512] = xsrc[tid + i * 512];
    ((float4*)(arena + w * AR))[ln] = ((const float4*)(x + (size_t)bglw * LL * KK))[ln];
    ((float4*)(arena + w * AR + 256))[ln] = make_float4(0.f, 0.f, 0.f, 0.f);
    __syncthreads();
    {
        float accr = 0.f;
        const float4* ain = (const float4*)(arena + bln * AR);
#pragma unroll 8
        for (int i = 0; i < 32; i++) {
            int idx = ks * 32 + ((i + 5 * ks) & 31);
            float4 a = ain[idx], q = rwc[idx];
            accr += a.x * q.x + a.y * q.y + a.z * q.z + a.w * q.w;
        }
        accr += __shfl_xor(accr, 8);
        accr += __shfl_xor(accr, 16);
        if (!(ln & 24)) sGr[c * 8 + bln] = accr + rb[col];
    }
    __syncthreads();
    if (tid < 32) {
        int pb = tid & 7, pj = tid >> 3;
        int bgp = bg * 8 + pb;
        float gi = sGr[(0 + pj) * 8 + pb], gG = sGr[(8 + pj) * 8 + pb];
        float go = sGr[(12 + pj) * 8 + pb];
        float cn = sigf(gi) * tanhf(gG);
        float hn = sigf(go) * tanhf(cn);
        crreg = cn;
        float hn2 = __shfl(hn, tid + 8);
        if (!(pj & 1)) st_coh2(hrb[0] + bgp * KK + j0 + pj, hn, hn2);
    }
    bar_arrive(fBo, 1u);
    float4 xreg = ((const float4*)(x + ((size_t)bglw * LL + 1) * KK))[ln];
    bar_wait(fB, 1u);

    for (int t = 0; t < LL; t++) {
        int cur = t & 1, prv = cur ^ 1;
        // ===== A-top: issue MALL loads =====
        const float* hp = hrb[cur] + bA * KK + ln * 4;
        float2 ha = ld_coh2(hp), hc = ld_coh2(hp + 2);
        float4 h4 = make_float4(ha.x, ha.y, hc.x, hc.y);
        float4 hrs2, hws2, w4 = make_float4(0.f, 0.f, 0.f, 0.f);
        {
            const float* hq = hrb[cur] + bglw * KK + ln * 4;
            float2 a = ld_coh2(hq), cc = ld_coh2(hq + 2);
            hrs2 = make_float4(a.x, a.y, cc.x, cc.y);
        }
        float Mprev = 0.f, invS = 0.f;
        if (t > 0) {
            const float* wp0 = hwb[prv] + bA * KK + ln * 4;
            float2 wa = ld_coh2(wp0), wc = ld_coh2(wp0 + 2);
            w4 = make_float4(wa.x, wa.y, wc.x, wc.y);
            const float* hq = hwb[prv] + bglw * KK + ln * 4;
            float2 a = ld_coh2(hq), cc = ld_coh2(hq + 2);
            hws2 = make_float4(a.x, a.y, cc.x, cc.y);
            Mprev = sMS[(bA & 7) * 2];
            invS = 1.0f / sMS[(bA & 7) * 2 + 1];
        } else {
            hws2 = make_float4(0.f, 0.f, 0.f, 0.f);
        }
        // ===== phase A: update + dots =====
        float dp[16];
        float* rowp = memT + w * 16 * KK;
        if (t > 0) {
            float scs[16];
            const float4* sp = (const float4*)(sScore + w * 16);
#pragma unroll
            for (int q2 = 0; q2 < 4; q2++) {
                float4 s4 = sp[q2];
                scs[q2 * 4 + 0] = s4.x; scs[q2 * 4 + 1] = s4.y;
                scs[q2 * 4 + 2] = s4.z; scs[q2 * 4 + 3] = s4.w;
            }
#pragma unroll
            for (int i = 0; i < 16; i++) {
                float4* vp = (float4*)(rowp + i * KK) + ln;
                float4 v = *vp;
                float z = __expf(scs[i] - Mprev) * invS;
                float om = 1.0f - z;
                v.x = v.x * om + w4.x * z;
                v.y = v.y * om + w4.y * z;
                v.z = v.z * om + w4.z * z;
                v.w = v.w * om + w4.w * z;
                *vp = v;
                dp[i] = h4.x * v.x + h4.y * v.y + h4.z * v.z + h4.w * v.w;
            }
        } else {
#pragma unroll
            for (int i = 0; i < 16; i++) {
                float4 v = *((float4*)(rowp + i * KK) + ln);
                dp[i] = h4.x * v.x + h4.y * v.y + h4.z * v.z + h4.w * v.w;
            }
        }
        // ===== transpose-reduce, stride 9 (conflict-free) =====
        {
            float* sT = arena + w * AR;
            int rr = ln >> 3, kk2 = ln & 7;
#pragma unroll
            for (int hh = 0; hh < 2; hh++) {
                int o = hh * 8;
#pragma unroll
                for (int j = 0; j < 8; j++) sT[ln * 9 + j] = dp[o + j];
                float ps = 0.f;
#pragma unroll
                for (int j = 0; j < 8; j++) ps += sT[(j * 8 + kk2) * 9 + rr];
                ps += __shfl_xor(ps, 1);
                ps += __shfl_xor(ps, 2);
                ps += __shfl_xor(ps, 4);
                if (kk2 == 0) sScore[w * 16 + o + rr] = ps;
            }
        }
        // ===== softmax partials =====
        {
            float scs2[16];
            const float4* sp = (const float4*)(sScore + w * 16);
#pragma unroll
            for (int q2 = 0; q2 < 4; q2++) {
                float4 s4 = sp[q2];
                scs2[q2 * 4 + 0] = s4.x; scs2[q2 * 4 + 1] = s4.y;
                scs2[q2 * 4 + 2] = s4.z; scs2[q2 * 4 + 3] = s4.w;
            }
            float M16 = scs2[0];
#pragma unroll
            for (int i = 1; i < 16; i++) M16 = fmaxf(M16, scs2[i]);
            float Sw = 0.f;
            float4 Vw = make_float4(0.f, 0.f, 0.f, 0.f);
#pragma unroll
            for (int i = 0; i < 16; i++) {
                float e = __expf(scs2[i] - M16);
                Sw += e;
                float4 v = *((float4*)(rowp + i * KK) + ln);
                Vw.x += e * v.x; Vw.y += e * v.y; Vw.z += e * v.z; Vw.w += e * v.w;
            }
            ((float4*)(arena + w * AR))[ln] = Vw;   // overwrites sT (reads done)
            if (ln == 0) { sMw[w] = M16; sSw[w] = Sw; }
        }
        __syncthreads();
        if (tid < 128) {
            float M = sMw[0];
#pragma unroll
            for (int q2 = 1; q2 < 8; q2++) M = fmaxf(M, sMw[q2]);
            float S = 0.f, V0 = 0.f, V1 = 0.f;
#pragma unroll
            for (int q2 = 0; q2 < 8; q2++) {
                float e = __expf(sMw[q2] - M);
                S += e * sSw[q2];
                V0 += e * arena[q2 * AR + 2 * tid];
                V1 += e * arena[q2 * AR + 2 * tid + 1];
            }
            st_coh2(partV + (size_t)g * KK + 2 * tid, V0, V1);
            if (tid == 0) st_coh2(partMS + g * 2, M, S);
        }
        bar_arrive(fAo, (unsigned)(t + 1));

        // ===== stage [x_{t+1} | hr_t | hw_{t-1}] into arena (per-wave b=bglw) =====
        if (t + 1 < LL) ((float4*)(arena + w * AR))[ln] = xreg;
        ((float4*)(arena + w * AR + 256))[ln] = hrs2;
        ((float4*)(arena + w * AR + 512))[ln] = hws2;
        __syncthreads();

        // ===== writer-pre stream: hr rows (fl4 0..63) + hw rows (fl4 128..191) =====
        float accw = (ks == 0) ? bfv[col] : 0.f;
        {
            const float4* ain = (const float4*)(arena + bln * AR);
#pragma unroll 8
            for (int i = 0; i < 16; i++) {
                int idx = ks * 16 + ((i + 3 * ks) & 15);
                float4 a = ain[64 + idx], q = wfc[idx];
                accw += a.x * q.x + a.y * q.y + a.z * q.z + a.w * q.w;
            }
#pragma unroll 8
            for (int i = 0; i < 16; i++) {
                int idx = ks * 16 + ((i + 3 * ks) & 15);
                float4 a = ain[128 + idx], q = wfc[128 + idx];
                accw += a.x * q.x + a.y * q.y + a.z * q.z + a.w * q.w;
            }
        }
        // ===== reader stream t+1: [x | hr] fl4 0..127 =====
        if (t + 1 < LL) {
            float accr = 0.f;
            const float4* ain = (const float4*)(arena + bln * AR);
#pragma unroll 8
            for (int i = 0; i < 32; i++) {
                int idx = ks * 32 + ((i + 5 * ks) & 31);
                float4 a = ain[idx], q = rwc[idx];
                accr += a.x * q.x + a.y * q.y + a.z * q.z + a.w * q.w;
            }
            accr += __shfl_xor(accr, 8);
            accr += __shfl_xor(accr, 16);
            if (!(ln & 24)) sGr[c * 8 + bln] = accr + rb[col];
        }
        __syncthreads();   // all arena x-reads done before combine overwrites

        // ===== per-wave waitA on this wave's 8 producer flags =====
        {
            unsigned tgt = (unsigned)(t + 1);
            for (;;) {
                unsigned v = tgt;
                if (ln < 8)
                    v = __hip_atomic_load(fA + (8 * w + ln) * FSTR, __ATOMIC_RELAXED, ASCOPE);
                if (__all(v >= tgt)) break;
                __builtin_amdgcn_s_sleep(1);
            }
        }
        // ===== gather + m_rt combine (wave w handles b=bglw) -> arena x-region =====
        {
            float2 pms[8];
            float2 pva[8], pvb[8];
#pragma unroll
            for (int q2 = 0; q2 < 8; q2++) {
                int src = bg * 64 + w * 8 + q2;
                pms[q2] = ld_coh2(partMS + src * 2);
                const float* pv = partV + (size_t)src * KK + ln * 4;
                pva[q2] = ld_coh2(pv);
                pvb[q2] = ld_coh2(pv + 2);
            }
            float M = pms[0].x;
#pragma unroll
            for (int q2 = 1; q2 < 8; q2++) M = fmaxf(M, pms[q2].x);
            float S = 0.f;
            float4 V = make_float4(0.f, 0.f, 0.f, 0.f);
#pragma unroll
            for (int q2 = 0; q2 < 8; q2++) {
                float e = __expf(pms[q2].x - M);
                S += e * pms[q2].y;
                V.x += e * pva[q2].x; V.y += e * pva[q2].y;
                V.z += e * pvb[q2].x; V.w += e * pvb[q2].y;
            }
            float rS = 1.0f / S;
            ((float4*)(arena + w * AR))[ln] =
                make_float4(V.x * rS, V.y * rS, V.z * rS, V.w * rS);
            if (ln == 0) { sMS[w * 2] = M; sMS[w * 2 + 1] = S; }
        }
        __syncthreads();   // m_rt + sGr visible to all

        // ===== B-post: m_rt @ Wf2 (register weights) + reduce -> sGw =====
        {
            const float4* ain = (const float4*)(arena + bln * AR);
#pragma unroll
            for (int i = 0; i < 16; i++) {
                int idx = ks * 16 + ((i + 3 * ks) & 15);
                float4 a = ain[idx];
                accw += a.x * w2[i].x + a.y * w2[i].y + a.z * w2[i].z + a.w * w2[i].w;
            }
            accw += __shfl_xor(accw, 8);
            accw += __shfl_xor(accw, 16);
            if (!(ln & 24)) sGw[c * 8 + bln] = accw;
        }
        __syncthreads();   // gates visible to wave0

        // ===== pointwise (wave0, tid<32): reader t+1 then writer t =====
        if (tid < 32) {
            int pb = tid & 7, pj = tid >> 3;
            int bgp = bg * 8 + pb;
            if (t + 1 < LL) {
                float gi = sGr[(0 + pj) * 8 + pb], gf = sGr[(4 + pj) * 8 + pb];
                float gG = sGr[(8 + pj) * 8 + pb], go = sGr[(12 + pj) * 8 + pb];
                float cn = sigf(gf) * crreg + sigf(gi) * tanhf(gG);
                float hn = sigf(go) * tanhf(cn);
                crreg = cn;
                float hn2 = __shfl(hn, tid + 8);
                if (!(pj & 1)) st_coh2(hrb[prv] + bgp * KK + j0 + pj, hn, hn2);
            }
            {
                float gi = sGw[(0 + pj) * 8 + pb], gf = sGw[(4 + pj) * 8 + pb];
                float gG = sGw[(8 + pj) * 8 + pb], go = sGw[(12 + pj) * 8 + pb];
                float cp2 = (t > 0) ? cwreg : 0.f;
                float cn = sigf(gf) * cp2 + sigf(gi) * tanhf(gG);
                float hn = sigf(go) * tanhf(cn);
                cwreg = cn;
                float hn2 = __shfl(hn, tid + 8);
                if (!(pj & 1)) {
                    st_coh2(hwb[cur] + bgp * KK + j0 + pj, hn, hn2);
                    *(float2*)(out + ((size_t)bgp * LL + t) * KK + j0 + pj) =
                        make_float2(hn, hn2);
                }
            }
        }
        bar_arrive(fBo, (unsigned)(t + 2));
        if (t + 2 < LL)
            xreg = ((const float4*)(x + ((size_t)bglw * LL + (size_t)(t + 2)) * KK))[ln];
        bar_wait(fB, (unsigned)(t + 2));
    }
}

// ---------------- host ----------------
extern "C" void kernel_launch(void* const* d_in, const int* in_sizes, int n_in,
                              void* d_out, int out_size, void* d_ws, size_t ws_size,
                              hipStream_t stream) {
    const float* x   = (const float*)d_in[0];
    const float* rWx = (const float*)d_in[1];
    const float* rWh = (const float*)d_in[2];
    const float* rb  = (const float*)d_in[3];
    const float* wWx = (const float*)d_in[4];
    const float* wWh = (const float*)d_in[5];
    const float* wb  = (const float*)d_in[6];
    const float* cW  = (const float*)d_in[7];
    const float* cb  = (const float*)d_in[8];
    float* out = (float*)d_out;

    float* ws = (float*)d_ws;
    float* WfT = ws;                        // 1024*768
    float* rWT = ws + 786432;               // 1024*512
    float* bfv = ws + 786432 + 524288;      // 1024
    float* st  = bfv + 1024;                // states + partials
    unsigned* flg = (unsigned*)(st + 98880);

    k_pre<<<932, 256, 0, stream>>>(cW, cb, wWx, wb, rWx, rWh, wWh, WfT, rWT, bfv, flg);

    const float* a_x = x; const float* a_rb = rb;
    const float* a_rWT = rWT; const float* a_WfT = WfT; const float* a_bf = bfv;
    float* a_st = st; float* a_out = out; unsigned* a_flg = flg;
    void* args[] = { &a_x, &a_rb, &a_rWT, &a_WfT, &a_bf, &a_st, &a_out, &a_flg };
    hipLaunchCooperativeKernel(reinterpret_cast<void*>(k_nse), dim3(256), dim3(512),
                               args, 0, stream);
}